// Round 8
// baseline (422.050 us; speedup 1.0000x reference)
//
#include <hip/hip_runtime.h>
#include <stdint.h>

#define EPSF 1e-6f

typedef unsigned short u16;
typedef __attribute__((ext_vector_type(8))) short short8;
typedef __attribute__((ext_vector_type(4))) float f32x4;

__device__ __forceinline__ float us2f(u16 u) {
  union { float f; unsigned int i; } c; c.i = ((unsigned int)u) << 16; return c.f;
}
__device__ __forceinline__ u16 f2bfu(float f) {
  union { float f; unsigned int i; } c; c.f = f;
  unsigned int i = c.i;
  return (u16)((i + 0x7FFFu + ((i >> 16) & 1u)) >> 16);
}
__device__ __forceinline__ float sigm(float x) { return 1.f / (1.f + __expf(-x)); }

typedef __attribute__((address_space(3))) unsigned int lds_u32;
typedef const __attribute__((address_space(1))) unsigned int glb_u32;
__device__ __forceinline__ void gl_lds16(const u16* g, u16* l) {
  __builtin_amdgcn_global_load_lds((glb_u32*)g, (lds_u32*)l, 16, 0, 0);
}

// ---------------- convert x (f32 -> bf16), 4 elems/thread ----------------
__global__ void k_cvt_x(const float* __restrict__ in, u16* __restrict__ out) {
  const int i = blockIdx.x * 256 + threadIdx.x;
  float4 v = ((const float4*)in)[i];
  ushort4 o;
  o.x = f2bfu(v.x); o.y = f2bfu(v.y); o.z = f2bfu(v.z); o.w = f2bfu(v.w);
  ((ushort4*)out)[i] = o;
}

// ---------------- transpose + convert: in f32 [R][C] -> out bf16 [C][R] ----------------
__global__ void k_transpose(const float* __restrict__ in, u16* __restrict__ out, int R, int C) {
  __shared__ float tile[32][33];
  const int tx = threadIdx.x & 31, ty = threadIdx.x >> 5;  // 32x8
  const int c0 = blockIdx.x << 5, r0 = blockIdx.y << 5;
  for (int i = ty; i < 32; i += 8) tile[i][tx] = in[(size_t)(r0 + i) * C + c0 + tx];
  __syncthreads();
  for (int i = ty; i < 32; i += 8) out[(size_t)(c0 + i) * R + r0 + tx] = f2bfu(tile[tx][i]);
}

// ---------------- GEMM: 256x256 tile, 8 waves (512t), BK=32, 4-slot LDS ring ----------------
// 8-phase-style schedule: each K-step split into 4 phases
//   {ds_read quadrant frags | 1 gl_lds stage chunk | s_barrier | lgkmcnt(0) | 8 MFMA | s_barrier}
// Counted vmcnt(8) once per step (retires tile kh+1; 8 newest stay in flight). Never vmcnt(0) in loop.
// Chunk swizzle within 64B rows (round-5-verified, 0 conflicts), pre-swizzled global source.
// MODE 0: flat qkv store (sigmoid q/k) + fused qsum/ksum. MODE 1: proj sigmoid(2x) f32 store.
template <int MODE>
__global__ __launch_bounds__(512, 2) void k_gemm(
    const u16* __restrict__ A, const u16* __restrict__ BT,
    const float* __restrict__ bias,
    u16* __restrict__ qkvo, float* __restrict__ qsum, float* __restrict__ ksum,
    float* __restrict__ outf)
{
  __shared__ __align__(16) u16 smem[65536];  // 128 KB
  const int tid = threadIdx.x;
  const int lane = tid & 63;
  const int wid = tid >> 6;           // 0..7
  const int wm = wid >> 2, wn = wid & 3;
  // bijective XCD swizzle (nwg % 8 == 0 for both grids)
  const int nx = gridDim.x;
  int lid = blockIdx.y * nx + blockIdx.x;
  const int q8 = (nx * gridDim.y) >> 3;
  lid = (lid & 7) * q8 + (lid >> 3);
  const int m0 = (lid / nx) << 8;
  const int n0 = (lid % nx) << 8;

  // ---- staging map: thread covers 16B chunks {tid, tid+512} of A-slot and B-slot ----
  const int rowS = tid >> 2;                       // 0..127 (chunk1: +128, (row>>1)&3 unchanged)
  const int sub  = tid & 3;
  const int subx = sub ^ ((rowS >> 1) & 3);        // pre-swizzled global k-chunk
  const u16* gA = A  + (size_t)(m0 + rowS) * 768 + (subx << 3);
  const u16* gB = BT + (size_t)(n0 + rowS) * 768 + (subx << 3);
  const int dstc = tid << 3;                       // elem offset of chunk tid

  // ---- read map ----
  const int r16 = lane & 15;
  const int sgrp = lane >> 4;                      // k chunk index (8 elems each)
  int offA[8], offB[4];
#pragma unroll
  for (int mi = 0; mi < 8; ++mi) {
    const int ra = (wm << 7) + (mi << 4) + r16;
    offA[mi] = ra * 32 + ((sgrp ^ ((ra >> 1) & 3)) << 3);
  }
#pragma unroll
  for (int nj = 0; nj < 4; ++nj) {
    const int rb = (wn << 6) + (nj << 4) + r16;
    offB[nj] = rb * 32 + ((sgrp ^ ((rb >> 1) & 3)) << 3);
  }

  f32x4 acc[8][4];
#pragma unroll
  for (int i = 0; i < 8; ++i)
#pragma unroll
    for (int j = 0; j < 4; ++j) acc[i][j] = (f32x4){0.f, 0.f, 0.f, 0.f};

  // one staging chunk (of 4 per K-tile); fixed issue order c=0..3 for vmcnt math
#define STAGE1(kh, c)                                                 \
  do {                                                                \
    const int khs = ((kh) > 23 ? 23 : (kh)) << 5;                     \
    const int so = ((kh) & 3) << 13;                                  \
    if ((c) == 0)      gl_lds16(gA + khs,          &smem[so + dstc]);             \
    else if ((c) == 1) gl_lds16(gA + 98304 + khs,  &smem[so + dstc + 4096]);      \
    else if ((c) == 2) gl_lds16(gB + khs,          &smem[32768 + so + dstc]);     \
    else               gl_lds16(gB + 98304 + khs,  &smem[32768 + so + dstc + 4096]); \
  } while (0)

  // prologue: tiles 0,1,2 staged (12 wave-loads outstanding)
#pragma unroll
  for (int t = 0; t < 3; ++t) {
    STAGE1(t, 0); STAGE1(t, 1); STAGE1(t, 2); STAGE1(t, 3);
  }
  asm volatile("s_waitcnt vmcnt(8)" ::: "memory");   // tile 0 landed (own loads)
  __builtin_amdgcn_s_barrier();                      // everyone's tile 0 landed

#define MFMA8(P, X0, X1)                                                                  \
  do {                                                                                    \
    acc[2*(P)][0] = __builtin_amdgcn_mfma_f32_16x16x32_bf16((X0), b0, acc[2*(P)][0], 0, 0, 0); \
    acc[2*(P)][1] = __builtin_amdgcn_mfma_f32_16x16x32_bf16((X0), b1, acc[2*(P)][1], 0, 0, 0); \
    acc[2*(P)][2] = __builtin_amdgcn_mfma_f32_16x16x32_bf16((X0), b2, acc[2*(P)][2], 0, 0, 0); \
    acc[2*(P)][3] = __builtin_amdgcn_mfma_f32_16x16x32_bf16((X0), b3, acc[2*(P)][3], 0, 0, 0); \
    acc[2*(P)+1][0] = __builtin_amdgcn_mfma_f32_16x16x32_bf16((X1), b0, acc[2*(P)+1][0], 0, 0, 0); \
    acc[2*(P)+1][1] = __builtin_amdgcn_mfma_f32_16x16x32_bf16((X1), b1, acc[2*(P)+1][1], 0, 0, 0); \
    acc[2*(P)+1][2] = __builtin_amdgcn_mfma_f32_16x16x32_bf16((X1), b2, acc[2*(P)+1][2], 0, 0, 0); \
    acc[2*(P)+1][3] = __builtin_amdgcn_mfma_f32_16x16x32_bf16((X1), b3, acc[2*(P)+1][3], 0, 0, 0); \
  } while (0)

  for (int kh = 0; kh < 24; ++kh) {
    const u16* pa = &smem[(kh & 3) << 13];
    const u16* pb = pa + 32768;

    // ---- phase 0: B frags + A rows 0-1 ----
    short8 b0 = *(const short8*)(pb + offB[0]);
    short8 b1 = *(const short8*)(pb + offB[1]);
    short8 b2 = *(const short8*)(pb + offB[2]);
    short8 b3 = *(const short8*)(pb + offB[3]);
    short8 a0 = *(const short8*)(pa + offA[0]);
    short8 a1 = *(const short8*)(pa + offA[1]);
    STAGE1(kh + 3, 0);
    __builtin_amdgcn_s_barrier();
    asm volatile("s_waitcnt lgkmcnt(0)" ::: "memory");
    __builtin_amdgcn_sched_barrier(0);
    __builtin_amdgcn_s_setprio(1);
    MFMA8(0, a0, a1);
    __builtin_amdgcn_s_setprio(0);
    __builtin_amdgcn_sched_barrier(0);
    __builtin_amdgcn_s_barrier();

    // ---- phase 1: A rows 2-3 ----
    a0 = *(const short8*)(pa + offA[2]);
    a1 = *(const short8*)(pa + offA[3]);
    STAGE1(kh + 3, 1);
    __builtin_amdgcn_s_barrier();
    asm volatile("s_waitcnt lgkmcnt(0)" ::: "memory");
    __builtin_amdgcn_sched_barrier(0);
    __builtin_amdgcn_s_setprio(1);
    MFMA8(1, a0, a1);
    __builtin_amdgcn_s_setprio(0);
    __builtin_amdgcn_sched_barrier(0);
    __builtin_amdgcn_s_barrier();

    // ---- phase 2: A rows 4-5 ----
    a0 = *(const short8*)(pa + offA[4]);
    a1 = *(const short8*)(pa + offA[5]);
    STAGE1(kh + 3, 2);
    __builtin_amdgcn_s_barrier();
    asm volatile("s_waitcnt lgkmcnt(0)" ::: "memory");
    __builtin_amdgcn_sched_barrier(0);
    __builtin_amdgcn_s_setprio(1);
    MFMA8(2, a0, a1);
    __builtin_amdgcn_s_setprio(0);
    __builtin_amdgcn_sched_barrier(0);
    __builtin_amdgcn_s_barrier();

    // ---- phase 3: A rows 6-7; counted vmcnt once per step ----
    a0 = *(const short8*)(pa + offA[6]);
    a1 = *(const short8*)(pa + offA[7]);
    STAGE1(kh + 3, 3);
    __builtin_amdgcn_s_barrier();
    asm volatile("s_waitcnt lgkmcnt(0)" ::: "memory");
    __builtin_amdgcn_sched_barrier(0);
    __builtin_amdgcn_s_setprio(1);
    MFMA8(3, a0, a1);
    __builtin_amdgcn_s_setprio(0);
    __builtin_amdgcn_sched_barrier(0);
    asm volatile("s_waitcnt vmcnt(8)" ::: "memory");   // tile kh+1 landed (12 out - 8)
    __builtin_amdgcn_s_barrier();
  }
#undef MFMA8
#undef STAGE1
  asm volatile("s_waitcnt vmcnt(0)" ::: "memory");  // drain phantom stages

  if (MODE == 0) {
    const int colc = n0 + (wn << 6);        // wave's 64-col window base
    const bool sg = (colc < 1536);          // uniform per wave: q/k vs v
    float jsum[4] = {0.f, 0.f, 0.f, 0.f};
#pragma unroll
    for (int mi = 0; mi < 8; ++mi) {
      const int rowb = m0 + (wm << 7) + (mi << 4) + ((lane >> 4) << 2);
#pragma unroll
      for (int nj = 0; nj < 4; ++nj) {
        const int col = colc + (nj << 4) + r16;
        const float bcol = bias[col];
        if (sg) {
#pragma unroll
          for (int rg = 0; rg < 4; ++rg) {
            const float val = sigm(acc[mi][nj][rg] + bcol);
            jsum[nj] += val;
            qkvo[(size_t)(rowb + rg) * 2304 + col] = f2bfu(val);
          }
        } else {
#pragma unroll
          for (int rg = 0; rg < 4; ++rg)
            qkvo[(size_t)(rowb + rg) * 2304 + col] = f2bfu(acc[mi][nj][rg] + bcol);
        }
      }
    }
    if (sg) {
#pragma unroll
      for (int nj = 0; nj < 4; ++nj) {
        jsum[nj] += __shfl_xor(jsum[nj], 16, 64);
        jsum[nj] += __shfl_xor(jsum[nj], 32, 64);
      }
      if (lane < 16) {
        const int b12 = (m0 >> 12) * 12;
        float* sdst = (colc >= 768) ? ksum : qsum;
        const int cb = (colc >= 768) ? colc - 768 : colc;  // 0..767 = h*64+d
#pragma unroll
        for (int nj = 0; nj < 4; ++nj)
          atomicAdd(&sdst[(b12 << 6) + cb + (nj << 4) + r16], jsum[nj]);
      }
    }
  } else {
#pragma unroll
    for (int mi = 0; mi < 8; ++mi) {
      const int rowb = m0 + (wm << 7) + (mi << 4) + ((lane >> 4) << 2);
#pragma unroll
      for (int nj = 0; nj < 4; ++nj) {
        const int col = n0 + (wn << 6) + (nj << 4) + r16;
        const float bcol = bias[col];
#pragma unroll
        for (int rg = 0; rg < 4; ++rg)
          outf[(size_t)(rowb + rg) * 768 + col] = sigm(2.f * (acc[mi][nj][rg] + bcol));
      }
    }
  }
}

// ---------------- si/so + qsi/kso (flat qkv layout) ----------------
__global__ __launch_bounds__(256) void k_flow1(
    const u16* __restrict__ qkv,
    const float* __restrict__ qsum, const float* __restrict__ ksum,
    float* __restrict__ si_out, float* __restrict__ qsi, float* __restrict__ kso)
{
  const int bh = blockIdx.x >> 3, sp = blockIdx.x & 7;
  const int lane = threadIdx.x & 63, wid = threadIdx.x >> 6;
  const int j = lane & 15;
  const int grp = (wid << 2) | (lane >> 4);
  const u16* base = qkv + (size_t)(bh / 12) * 4096 * 2304 + (bh % 12) * 64;
  float ke[4], qe[4];
#pragma unroll
  for (int t = 0; t < 4; ++t) {
    ke[t] = ksum[(bh << 6) + (j << 2) + t] + EPSF;
    qe[t] = qsum[(bh << 6) + (j << 2) + t] + EPSF;
  }
  float Sk = ke[0] + ke[1] + ke[2] + ke[3];
  float Sq = qe[0] + qe[1] + qe[2] + qe[3];
#pragma unroll
  for (int msk = 1; msk < 16; msk <<= 1) { Sk += __shfl_xor(Sk, msk, 64); Sq += __shfl_xor(Sq, msk, 64); }
  const float cK = EPSF * Sk + EPSF;
  const float cQ = EPSF * Sq + EPSF;
  float aq0 = 0, aq1 = 0, aq2 = 0, aq3 = 0, ak0 = 0, ak1 = 0, ak2 = 0, ak3 = 0;
  const int nbase = sp << 9;
  for (int it = 0; it < 32; ++it) {
    const int n = nbase + (it << 4) + grp;
    const size_t ro = (size_t)n * 2304 + (j << 2);
    const uint64_t lq = *(const uint64_t*)(base + ro);
    const uint64_t lk = *(const uint64_t*)(base + ro + 768);
    const float q0 = us2f((u16)lq), q1 = us2f((u16)(lq >> 16)), q2 = us2f((u16)(lq >> 32)), q3 = us2f((u16)(lq >> 48));
    const float k0 = us2f((u16)lk), k1 = us2f((u16)(lk >> 16)), k2 = us2f((u16)(lk >> 32)), k3 = us2f((u16)(lk >> 48));
    float dq = q0 * ke[0] + q1 * ke[1] + q2 * ke[2] + q3 * ke[3];
    float dk = k0 * qe[0] + k1 * qe[1] + k2 * qe[2] + k3 * qe[3];
#pragma unroll
    for (int msk = 1; msk < 16; msk <<= 1) { dq += __shfl_xor(dq, msk, 64); dk += __shfl_xor(dk, msk, 64); }
    const float si = 1.f / (dq + cK);
    const float so = 1.f / (dk + cQ);
    if (j == 0) si_out[(bh << 12) + n] = si;
    aq0 += q0 * si; aq1 += q1 * si; aq2 += q2 * si; aq3 += q3 * si;
    ak0 += k0 * so; ak1 += k1 * so; ak2 += k2 * so; ak3 += k3 * so;
  }
  __shared__ float redq[16][64];
  __shared__ float redk[16][64];
  redq[grp][(j << 2) + 0] = aq0; redq[grp][(j << 2) + 1] = aq1;
  redq[grp][(j << 2) + 2] = aq2; redq[grp][(j << 2) + 3] = aq3;
  redk[grp][(j << 2) + 0] = ak0; redk[grp][(j << 2) + 1] = ak1;
  redk[grp][(j << 2) + 2] = ak2; redk[grp][(j << 2) + 3] = ak3;
  __syncthreads();
  if (threadIdx.x < 64) {
    float s1 = 0.f, s2 = 0.f;
#pragma unroll
    for (int g = 0; g < 16; ++g) { s1 += redq[g][threadIdx.x]; s2 += redk[g][threadIdx.x]; }
    atomicAdd(&qsi[(bh << 6) + threadIdx.x], s1);
    atomicAdd(&kso[(bh << 6) + threadIdx.x], s2);
  }
}

// ---------------- fused flow2 + kv (MFMA): e/m/sumexp inline, kvm[d][e] accumulate ----------------
__global__ __launch_bounds__(256) void k_fkv(
    const u16* __restrict__ qkv,
    const float* __restrict__ qsi, const float* __restrict__ kso,
    const float* __restrict__ si_in,
    float* __restrict__ mo, float* __restrict__ sumexp, float* __restrict__ kvm)
{
  __shared__ __align__(16) u16 smem[2 * 64 * 136];  // 34816 B; reused as f32 reduce buf
  u16* kT = smem;
  u16* vT = smem + 64 * 136;
  const int tid = threadIdx.x;
  const int bh = blockIdx.x >> 3, sp = blockIdx.x & 7;
  const int lane = tid & 63, wid = tid >> 6;
  const int r16 = lane & 15, g = lane >> 4;
  const u16* base = qkv + (size_t)(bh / 12) * 4096 * 2304 + (bh % 12) * 64;
  const float* sib = si_in + ((size_t)bh << 12);
  float* mob = mo + ((size_t)bh << 12);

  // per-thread d-slice (constant across stages/iters)
  const int d0 = (tid & 7) << 3;
  float qie[8], soe[8];
#pragma unroll
  for (int u = 0; u < 8; ++u) {
    qie[u] = qsi[(bh << 6) + d0 + u] + EPSF;
    soe[u] = kso[(bh << 6) + d0 + u] + EPSF;
  }
  // block-uniform eps terms: cR = eps*sum(qsi+eps)+eps, cS = eps*sum(kso+eps)+eps
  float Sq = qsi[(bh << 6) + lane] + EPSF;
  float Sk = kso[(bh << 6) + lane] + EPSF;
#pragma unroll
  for (int m = 1; m < 64; m <<= 1) { Sq += __shfl_xor(Sq, m, 64); Sk += __shfl_xor(Sk, m, 64); }
  const float cR = EPSF * Sq + EPSF;
  const float cS = EPSF * Sk + EPSF;

  f32x4 acc[4][4];
#pragma unroll
  for (int i = 0; i < 4; ++i)
#pragma unroll
    for (int j = 0; j < 4; ++j) acc[i][j] = (f32x4){0.f, 0.f, 0.f, 0.f};

  const int nf = (wid << 5) + (g << 3);  // wave n-window + lane-group k offset
  float esum = 0.f;

  for (int st = 0; st < 4; ++st) {
    const int nst = (sp << 9) + (st << 7);
#pragma unroll
    for (int i = 0; i < 4; ++i) {
      const int c = tid + (i << 8);
      const int nl = c >> 3;              // 0..127
      const int ng = nst + nl;
      const u16* rp = base + (size_t)ng * 2304 + d0;
      short8 q8 = *(const short8*)(rp);
      short8 k8 = *(const short8*)(rp + 768);
      short8 v8 = *(const short8*)(rp + 1536);
      float pcs = 0.f, pcr = 0.f;
#pragma unroll
      for (int u = 0; u < 8; ++u) {
        pcs += us2f((u16)q8[u]) * soe[u];
        pcr += us2f((u16)k8[u]) * qie[u];
      }
#pragma unroll
      for (int m = 1; m < 8; m <<= 1) { pcs += __shfl_xor(pcs, m, 64); pcr += __shfl_xor(pcr, m, 64); }
      float cr = pcr + cR;
      cr = fminf(1.f, fmaxf(-1.f, cr));
      const float ev = __expf(cr);
      const int col = nl ^ (d0 & 56);     // write-side XOR swizzle (proven, round 3)
#pragma unroll
      for (int u = 0; u < 8; ++u) {
        kT[(d0 + u) * 136 + col] = f2bfu(us2f((u16)k8[u]) * ev);
        vT[(d0 + u) * 136 + col] = (u16)(unsigned short)v8[u];
      }
      if ((tid & 7) == 0) {
        mob[ng] = sib[ng] * sigm(pcs + cS);
        esum += ev;
      }
    }
    __syncthreads();

    short8 af[4], bf[4];
#pragma unroll
    for (int mi = 0; mi < 4; ++mi) {
      const int row = (mi << 4) + r16;
      af[mi] = *(const short8*)&kT[row * 136 + (nf ^ (row & 56))];
    }
#pragma unroll
    for (int nj = 0; nj < 4; ++nj) {
      const int row = (nj << 4) + r16;
      bf[nj] = *(const short8*)&vT[row * 136 + (nf ^ (row & 56))];
    }
#pragma unroll
    for (int mi = 0; mi < 4; ++mi)
#pragma unroll
      for (int nj = 0; nj < 4; ++nj)
        acc[mi][nj] = __builtin_amdgcn_mfma_f32_16x16x32_bf16(af[mi], bf[nj], acc[mi][nj], 0, 0, 0);
    __syncthreads();
  }

  // cross-wave reduce (two 32-d halves through LDS) + coalesced atomics
  float* red = (float*)smem;
  float* kvb = kvm + ((size_t)bh << 12);
#pragma unroll
  for (int half = 0; half < 2; ++half) {
#pragma unroll
    for (int m2 = 0; m2 < 2; ++m2) {
      const int mi = (half << 1) + m2;
#pragma unroll
      for (int nj = 0; nj < 4; ++nj)
#pragma unroll
        for (int rg = 0; rg < 4; ++rg)
          red[(wid << 11) + (((m2 << 4) + (g << 2) + rg) << 6) + (nj << 4) + r16] = acc[mi][nj][rg];
    }
    __syncthreads();
    const int base2 = tid << 3;
#pragma unroll
    for (int u2 = 0; u2 < 2; ++u2) {
      const int o = base2 + (u2 << 2);
      float4 s0 = *(const float4*)&red[o];
      float4 s1 = *(const float4*)&red[2048 + o];
      float4 s2 = *(const float4*)&red[4096 + o];
      float4 s3 = *(const float4*)&red[6144 + o];
      s0.x += s1.x + s2.x + s3.x;
      s0.y += s1.y + s2.y + s3.y;
      s0.z += s1.z + s2.z + s3.z;
      s0.w += s1.w + s2.w + s3.w;
      const int gi = (half << 11) + o;
      atomicAdd(&kvb[gi + 0], s0.x);
      atomicAdd(&kvb[gi + 1], s0.y);
      atomicAdd(&kvb[gi + 2], s0.z);
      atomicAdd(&kvb[gi + 3], s0.w);
    }
    __syncthreads();
  }

  // sumexp: lanes 0,8,...,56 hold partials; fold within wave, 1 atomic/wave
  esum += __shfl_xor(esum, 8, 64);
  esum += __shfl_xor(esum, 16, 64);
  esum += __shfl_xor(esum, 32, 64);
  if (lane == 0) atomicAdd(&sumexp[bh], esum);
}

// ---------------- x_update = (q @ kv) * m[n] * scale -> attn [B][N][C] bf16 (MFMA) ----------------
__global__ __launch_bounds__(256) void k_xup(
    const u16* __restrict__ qkv, const float* __restrict__ kvm,
    const float* __restrict__ m_arr, const float* __restrict__ sumexp,
    u16* __restrict__ attn)
{
  const int bh = blockIdx.y;
  const int n0 = blockIdx.x << 7;
  const int b = bh / 12, h = bh % 12;
  __shared__ __align__(16) u16 qs[128 * 72];   // stride 72 elems (144B): 2-way banks, 16B aligned
  __shared__ __align__(16) u16 kvs[64 * 72];   // kv^T as [e][d] bf16
  const int tid = threadIdx.x, lane = tid & 63, wid = tid >> 6;
  const u16* qg = qkv + (size_t)b * 4096 * 2304 + (size_t)n0 * 2304 + h * 64;
#pragma unroll
  for (int i = 0; i < 4; ++i) {
    const int c = tid + (i << 8);
    const int nl = c >> 3, d0 = (c & 7) << 3;
    *(short8*)&qs[nl * 72 + d0] = *(const short8*)(qg + (size_t)nl * 2304 + d0);
  }
  const float* kvg = kvm + ((size_t)bh << 12);
#pragma unroll
  for (int i = 0; i < 4; ++i) {
    const int idx = (tid << 2) + (i << 10);
    const int d = idx >> 6, e0 = idx & 63;
    float4 vv = *(const float4*)(kvg + idx);
    kvs[(e0 + 0) * 72 + d] = f2bfu(vv.x);
    kvs[(e0 + 1) * 72 + d] = f2bfu(vv.y);
    kvs[(e0 + 2) * 72 + d] = f2bfu(vv.z);
    kvs[(e0 + 3) * 72 + d] = f2bfu(vv.w);
  }
  __syncthreads();
  const float scale = 4096.f / sumexp[bh];
  const int r16 = lane & 15, kg8 = (lane >> 4) << 3;
  f32x4 acc[2][4];
#pragma unroll
  for (int i = 0; i < 2; ++i)
#pragma unroll
    for (int j = 0; j < 4; ++j) acc[i][j] = (f32x4){0.f, 0.f, 0.f, 0.f};
#pragma unroll
  for (int kk = 0; kk < 2; ++kk) {
    short8 af[2], bfv[4];
#pragma unroll
    for (int mi = 0; mi < 2; ++mi)
      af[mi] = *(const short8*)&qs[((wid << 5) + (mi << 4) + r16) * 72 + (kk << 5) + kg8];
#pragma unroll
    for (int nj = 0; nj < 4; ++nj)
      bfv[nj] = *(const short8*)&kvs[((nj << 4) + r16) * 72 + (kk << 5) + kg8];
#pragma unroll
    for (int mi = 0; mi < 2; ++mi)
#pragma unroll
      for (int nj = 0; nj < 4; ++nj)
        acc[mi][nj] = __builtin_amdgcn_mfma_f32_16x16x32_bf16(af[mi], bfv[nj], acc[mi][nj], 0, 0, 0);
  }
#pragma unroll
  for (int mi = 0; mi < 2; ++mi) {
#pragma unroll
    for (int rg = 0; rg < 4; ++rg) {
      const int n = n0 + (wid << 5) + (mi << 4) + ((lane >> 4) << 2) + rg;
      const float mult = m_arr[((size_t)bh << 12) + n] * scale;
#pragma unroll
      for (int nj = 0; nj < 4; ++nj) {
        const int e = (nj << 4) + r16;
        attn[((size_t)(b * 4096 + n)) * 768 + (h << 6) + e] = f2bfu(acc[mi][nj][rg] * mult);
      }
    }
  }
}

extern "C" void kernel_launch(void* const* d_in, const int* in_sizes, int n_in,
                              void* d_out, int out_size, void* d_ws, size_t ws_size,
                              hipStream_t stream)
{
  (void)in_sizes; (void)n_in; (void)out_size; (void)ws_size;
  const float* x     = (const float*)d_in[0];
  const float* Wqkv  = (const float*)d_in[1];
  const float* bqkv  = (const float*)d_in[2];
  const float* Wproj = (const float*)d_in[3];
  const float* bproj = (const float*)d_in[4];
  float* out = (float*)d_out;

  char* ws = (char*)d_ws;
  size_t off = 0;
  auto alloc = [&](size_t bytes) -> char* {
    char* p = ws + off;
    off += (bytes + 255) & ~(size_t)255;
    return p;
  };
  u16* qkv  = (u16*)alloc(150994944);      // [32768][2304] bf16 flat (q|k|v)
  u16* xbf  = (u16*)alloc(50331648);       // x bf16; reused as attn output
  u16* WqT  = (u16*)alloc(3538944);        // [2304][768] bf16
  u16* WpT  = (u16*)alloc(1179648);        // [768][768] bf16
  float* si = (float*)alloc(1572864);      // [B*H][N]
  float* mb = (float*)alloc(1572864);      // si * sink_allocation
  char* zbase = ws + off;
  float* qsum   = (float*)alloc(24576);
  float* ksum   = (float*)alloc(24576);
  float* qsi    = (float*)alloc(24576);
  float* kso    = (float*)alloc(24576);
  float* sumexp = (float*)alloc(512);
  float* kvm    = (float*)alloc(1572864);  // [B*H][64 d][64 e] f32
  const size_t zbytes = (size_t)((ws + off) - zbase);

  hipMemsetAsync(zbase, 0, zbytes, stream);
  k_cvt_x<<<24576, 256, 0, stream>>>(x, xbf);
  k_transpose<<<dim3(72, 24), 256, 0, stream>>>(Wqkv, WqT, 768, 2304);
  k_transpose<<<dim3(24, 24), 256, 0, stream>>>(Wproj, WpT, 768, 768);
  k_gemm<0><<<dim3(9, 128), 512, 0, stream>>>(xbf, WqT, bqkv, qkv, qsum, ksum, nullptr);
  k_flow1<<<768, 256, 0, stream>>>(qkv, qsum, ksum, si, qsi, kso);
  k_fkv<<<768, 256, 0, stream>>>(qkv, qsi, kso, si, mb, sumexp, kvm);
  k_xup<<<dim3(32, 96), 256, 0, stream>>>(qkv, kvm, mb, sumexp, xbf);
  k_gemm<1><<<dim3(3, 128), 512, 0, stream>>>(xbf, WpT, bproj, nullptr, nullptr, nullptr, out);
}

// Round 9
// 411.997 us; speedup vs baseline: 1.0244x; 1.0244x over previous
//
#include <hip/hip_runtime.h>
#include <stdint.h>

#define EPSF 1e-6f

typedef unsigned short u16;
typedef __attribute__((ext_vector_type(8))) short short8;
typedef __attribute__((ext_vector_type(4))) float f32x4;

__device__ __forceinline__ float us2f(u16 u) {
  union { float f; unsigned int i; } c; c.i = ((unsigned int)u) << 16; return c.f;
}
__device__ __forceinline__ u16 f2bfu(float f) {
  union { float f; unsigned int i; } c; c.f = f;
  unsigned int i = c.i;
  return (u16)((i + 0x7FFFu + ((i >> 16) & 1u)) >> 16);
}
__device__ __forceinline__ float sigm(float x) { return 1.f / (1.f + __expf(-x)); }

typedef __attribute__((address_space(3))) unsigned int lds_u32;
typedef const __attribute__((address_space(1))) unsigned int glb_u32;
__device__ __forceinline__ void gl_lds16(const u16* g, u16* l) {
  __builtin_amdgcn_global_load_lds((glb_u32*)g, (lds_u32*)l, 16, 0, 0);
}

// ---------------- convert x (f32 -> bf16), 4 elems/thread ----------------
__global__ void k_cvt_x(const float* __restrict__ in, u16* __restrict__ out) {
  const int i = blockIdx.x * 256 + threadIdx.x;
  float4 v = ((const float4*)in)[i];
  ushort4 o;
  o.x = f2bfu(v.x); o.y = f2bfu(v.y); o.z = f2bfu(v.z); o.w = f2bfu(v.w);
  ((ushort4*)out)[i] = o;
}

// ---------------- transpose + convert: in f32 [R][C] -> out bf16 [C][R] ----------------
__global__ void k_transpose(const float* __restrict__ in, u16* __restrict__ out, int R, int C) {
  __shared__ float tile[32][33];
  const int tx = threadIdx.x & 31, ty = threadIdx.x >> 5;  // 32x8
  const int c0 = blockIdx.x << 5, r0 = blockIdx.y << 5;
  for (int i = ty; i < 32; i += 8) tile[i][tx] = in[(size_t)(r0 + i) * C + c0 + tx];
  __syncthreads();
  for (int i = ty; i < 32; i += 8) out[(size_t)(c0 + i) * R + r0 + tx] = f2bfu(tile[tx][i]);
}

// ---------------- GEMM: 256x256 tile, 8 waves (512t), BK=32, 4-slot LDS ring ----------------
// Round-7 proven structure (best measured: 170.5us). Counted vmcnt(8), prefetch
// distance 3 K-steps, one s_barrier per step (no drain in loop). Chunk swizzle
// within 64B rows (round-5-verified, 0 conflicts), pre-swizzled global source.
// MODE 0: flat qkv store (sigmoid q/k) + fused qsum/ksum. MODE 1: proj sigmoid(2x) f32 store.
template <int MODE>
__global__ __launch_bounds__(512, 2) void k_gemm(
    const u16* __restrict__ A, const u16* __restrict__ BT,
    const float* __restrict__ bias,
    u16* __restrict__ qkvo, float* __restrict__ qsum, float* __restrict__ ksum,
    float* __restrict__ outf)
{
  __shared__ __align__(16) u16 smem[65536];  // 128 KB
  const int tid = threadIdx.x;
  const int lane = tid & 63;
  const int wid = tid >> 6;           // 0..7
  const int wm = wid >> 2, wn = wid & 3;
  // bijective XCD swizzle (nwg % 8 == 0 for both grids)
  const int nx = gridDim.x;
  int lid = blockIdx.y * nx + blockIdx.x;
  const int q8 = (nx * gridDim.y) >> 3;
  lid = (lid & 7) * q8 + (lid >> 3);
  const int m0 = (lid / nx) << 8;
  const int n0 = (lid % nx) << 8;

  // ---- staging map: thread covers 16B chunks {tid, tid+512} of A-slot and B-slot ----
  const int rowS = tid >> 2;                       // 0..127 (chunk1: +128, (row>>1)&3 unchanged)
  const int sub  = tid & 3;
  const int subx = sub ^ ((rowS >> 1) & 3);        // pre-swizzled global k-chunk
  const u16* gA = A  + (size_t)(m0 + rowS) * 768 + (subx << 3);
  const u16* gB = BT + (size_t)(n0 + rowS) * 768 + (subx << 3);
  const int dstc = tid << 3;                       // elem offset of chunk tid

  // ---- read map ----
  const int r16 = lane & 15;
  const int sgrp = lane >> 4;                      // k chunk index (8 elems each)
  int offA[8], offB[4];
#pragma unroll
  for (int mi = 0; mi < 8; ++mi) {
    const int ra = (wm << 7) + (mi << 4) + r16;
    offA[mi] = ra * 32 + ((sgrp ^ ((ra >> 1) & 3)) << 3);
  }
#pragma unroll
  for (int nj = 0; nj < 4; ++nj) {
    const int rb = (wn << 6) + (nj << 4) + r16;
    offB[nj] = rb * 32 + ((sgrp ^ ((rb >> 1) & 3)) << 3);
  }

  f32x4 acc[8][4];
#pragma unroll
  for (int i = 0; i < 8; ++i)
#pragma unroll
    for (int j = 0; j < 4; ++j) acc[i][j] = (f32x4){0.f, 0.f, 0.f, 0.f};

#define STAGE(kh)                                                   \
  do {                                                              \
    const int khs = ((kh) > 23 ? 23 : (kh)) << 5;                   \
    const int so = ((kh) & 3) << 13;                                \
    gl_lds16(gA + khs,         &smem[so + dstc]);                   \
    gl_lds16(gA + 98304 + khs, &smem[so + dstc + 4096]);            \
    gl_lds16(gB + khs,         &smem[32768 + so + dstc]);           \
    gl_lds16(gB + 98304 + khs, &smem[32768 + so + dstc + 4096]);    \
  } while (0)

  STAGE(0); STAGE(1); STAGE(2);

  for (int kh = 0; kh < 24; ++kh) {
    asm volatile("s_waitcnt vmcnt(8)" ::: "memory");   // tile kh landed (12 outstanding - 8)
    __builtin_amdgcn_s_barrier();                      // everyone's tile kh landed; prev reads retired
    __builtin_amdgcn_sched_barrier(0);
    STAGE(kh + 3);                                     // slot (kh+3)&3 == (kh-1)&3: free since barrier
    const u16* pa = &smem[(kh & 3) << 13];
    const u16* pb = pa + 32768;
    short8 bf[4];
#pragma unroll
    for (int nj = 0; nj < 4; ++nj) bf[nj] = *(const short8*)(pb + offB[nj]);
    __builtin_amdgcn_s_setprio(1);
#pragma unroll
    for (int mi = 0; mi < 8; ++mi) {
      const short8 av = *(const short8*)(pa + offA[mi]);
#pragma unroll
      for (int nj = 0; nj < 4; ++nj)
        acc[mi][nj] = __builtin_amdgcn_mfma_f32_16x16x32_bf16(av, bf[nj], acc[mi][nj], 0, 0, 0);
    }
    __builtin_amdgcn_s_setprio(0);
  }
#undef STAGE
  asm volatile("s_waitcnt vmcnt(0)" ::: "memory");  // drain phantom stages

  if (MODE == 0) {
    const int colc = n0 + (wn << 6);        // wave's 64-col window base
    const bool sg = (colc < 1536);          // uniform per wave: q/k vs v
    float jsum[4] = {0.f, 0.f, 0.f, 0.f};
#pragma unroll
    for (int mi = 0; mi < 8; ++mi) {
      const int rowb = m0 + (wm << 7) + (mi << 4) + ((lane >> 4) << 2);
#pragma unroll
      for (int nj = 0; nj < 4; ++nj) {
        const int col = colc + (nj << 4) + r16;
        const float bcol = bias[col];
        if (sg) {
#pragma unroll
          for (int rg = 0; rg < 4; ++rg) {
            const float val = sigm(acc[mi][nj][rg] + bcol);
            jsum[nj] += val;
            qkvo[(size_t)(rowb + rg) * 2304 + col] = f2bfu(val);
          }
        } else {
#pragma unroll
          for (int rg = 0; rg < 4; ++rg)
            qkvo[(size_t)(rowb + rg) * 2304 + col] = f2bfu(acc[mi][nj][rg] + bcol);
        }
      }
    }
    if (sg) {
#pragma unroll
      for (int nj = 0; nj < 4; ++nj) {
        jsum[nj] += __shfl_xor(jsum[nj], 16, 64);
        jsum[nj] += __shfl_xor(jsum[nj], 32, 64);
      }
      if (lane < 16) {
        const int b12 = (m0 >> 12) * 12;
        float* sdst = (colc >= 768) ? ksum : qsum;
        const int cb = (colc >= 768) ? colc - 768 : colc;  // 0..767 = h*64+d
#pragma unroll
        for (int nj = 0; nj < 4; ++nj)
          atomicAdd(&sdst[(b12 << 6) + cb + (nj << 4) + r16], jsum[nj]);
      }
    }
  } else {
#pragma unroll
    for (int mi = 0; mi < 8; ++mi) {
      const int rowb = m0 + (wm << 7) + (mi << 4) + ((lane >> 4) << 2);
#pragma unroll
      for (int nj = 0; nj < 4; ++nj) {
        const int col = n0 + (wn << 6) + (nj << 4) + r16;
        const float bcol = bias[col];
#pragma unroll
        for (int rg = 0; rg < 4; ++rg)
          outf[(size_t)(rowb + rg) * 768 + col] = sigm(2.f * (acc[mi][nj][rg] + bcol));
      }
    }
  }
}

// ---------------- si/so + qsi/kso: 8-lane groups, 16B loads (fkv-pattern) ----------------
__global__ __launch_bounds__(256) void k_flow1(
    const u16* __restrict__ qkv,
    const float* __restrict__ qsum, const float* __restrict__ ksum,
    float* __restrict__ si_out, float* __restrict__ qsi, float* __restrict__ kso)
{
  const int bh = blockIdx.x >> 3, sp = blockIdx.x & 7;
  const int tid = threadIdx.x;
  const int grp = tid >> 3;            // 0..31 (row group)
  const int d0 = (tid & 7) << 3;       // 8-elem d-slice
  const u16* base = qkv + (size_t)(bh / 12) * 4096 * 2304 + (bh % 12) * 64;

  float ke[8], qe[8];
#pragma unroll
  for (int u = 0; u < 8; ++u) {
    ke[u] = ksum[(bh << 6) + d0 + u] + EPSF;
    qe[u] = qsum[(bh << 6) + d0 + u] + EPSF;
  }
  float Sk = 0.f, Sq = 0.f;
#pragma unroll
  for (int u = 0; u < 8; ++u) { Sk += ke[u]; Sq += qe[u]; }
#pragma unroll
  for (int m = 1; m < 8; m <<= 1) { Sk += __shfl_xor(Sk, m, 64); Sq += __shfl_xor(Sq, m, 64); }
  const float cK = EPSF * Sk + EPSF;
  const float cQ = EPSF * Sq + EPSF;

  float aq[8], ak[8];
#pragma unroll
  for (int u = 0; u < 8; ++u) { aq[u] = 0.f; ak[u] = 0.f; }

  const int nbase = sp << 9;
  for (int it = 0; it < 16; ++it) {
    const int n = nbase + (it << 5) + grp;
    const u16* rp = base + (size_t)n * 2304 + d0;
    short8 q8 = *(const short8*)(rp);
    short8 k8 = *(const short8*)(rp + 768);
    float dq = 0.f, dk = 0.f;
#pragma unroll
    for (int u = 0; u < 8; ++u) {
      dq += us2f((u16)q8[u]) * ke[u];
      dk += us2f((u16)k8[u]) * qe[u];
    }
#pragma unroll
    for (int m = 1; m < 8; m <<= 1) { dq += __shfl_xor(dq, m, 64); dk += __shfl_xor(dk, m, 64); }
    const float si = 1.f / (dq + cK);
    const float so = 1.f / (dk + cQ);
    if ((tid & 7) == 0) si_out[(bh << 12) + n] = si;
#pragma unroll
    for (int u = 0; u < 8; ++u) {
      aq[u] += us2f((u16)q8[u]) * si;
      ak[u] += us2f((u16)k8[u]) * so;
    }
  }
  __shared__ float redq[32][68];
  __shared__ float redk[32][68];
#pragma unroll
  for (int u = 0; u < 8; ++u) { redq[grp][d0 + u] = aq[u]; redk[grp][d0 + u] = ak[u]; }
  __syncthreads();
  if (tid < 128) {
    const int which = tid >> 6, d = tid & 63;
    float s = 0.f;
    if (which == 0) {
#pragma unroll
      for (int g = 0; g < 32; ++g) s += redq[g][d];
      atomicAdd(&qsi[(bh << 6) + d], s);
    } else {
#pragma unroll
      for (int g = 0; g < 32; ++g) s += redk[g][d];
      atomicAdd(&kso[(bh << 6) + d], s);
    }
  }
}

// ---------------- fused flow2 + kv (MFMA): e/m/sumexp inline, kvm[d][e] accumulate ----------------
__global__ __launch_bounds__(256) void k_fkv(
    const u16* __restrict__ qkv,
    const float* __restrict__ qsi, const float* __restrict__ kso,
    const float* __restrict__ si_in,
    float* __restrict__ mo, float* __restrict__ sumexp, float* __restrict__ kvm)
{
  __shared__ __align__(16) u16 smem[2 * 64 * 136];  // 34816 B; reused as f32 reduce buf
  u16* kT = smem;
  u16* vT = smem + 64 * 136;
  const int tid = threadIdx.x;
  const int bh = blockIdx.x >> 3, sp = blockIdx.x & 7;
  const int lane = tid & 63, wid = tid >> 6;
  const int r16 = lane & 15, g = lane >> 4;
  const u16* base = qkv + (size_t)(bh / 12) * 4096 * 2304 + (bh % 12) * 64;
  const float* sib = si_in + ((size_t)bh << 12);
  float* mob = mo + ((size_t)bh << 12);

  // per-thread d-slice (constant across stages/iters)
  const int d0 = (tid & 7) << 3;
  float qie[8], soe[8];
#pragma unroll
  for (int u = 0; u < 8; ++u) {
    qie[u] = qsi[(bh << 6) + d0 + u] + EPSF;
    soe[u] = kso[(bh << 6) + d0 + u] + EPSF;
  }
  // block-uniform eps terms: cR = eps*sum(qsi+eps)+eps, cS = eps*sum(kso+eps)+eps
  float Sq = qsi[(bh << 6) + lane] + EPSF;
  float Sk = kso[(bh << 6) + lane] + EPSF;
#pragma unroll
  for (int m = 1; m < 64; m <<= 1) { Sq += __shfl_xor(Sq, m, 64); Sk += __shfl_xor(Sk, m, 64); }
  const float cR = EPSF * Sq + EPSF;
  const float cS = EPSF * Sk + EPSF;

  f32x4 acc[4][4];
#pragma unroll
  for (int i = 0; i < 4; ++i)
#pragma unroll
    for (int j = 0; j < 4; ++j) acc[i][j] = (f32x4){0.f, 0.f, 0.f, 0.f};

  const int nf = (wid << 5) + (g << 3);  // wave n-window + lane-group k offset
  float esum = 0.f;

  for (int st = 0; st < 4; ++st) {
    const int nst = (sp << 9) + (st << 7);
#pragma unroll
    for (int i = 0; i < 4; ++i) {
      const int c = tid + (i << 8);
      const int nl = c >> 3;              // 0..127
      const int ng = nst + nl;
      const u16* rp = base + (size_t)ng * 2304 + d0;
      short8 q8 = *(const short8*)(rp);
      short8 k8 = *(const short8*)(rp + 768);
      short8 v8 = *(const short8*)(rp + 1536);
      float pcs = 0.f, pcr = 0.f;
#pragma unroll
      for (int u = 0; u < 8; ++u) {
        pcs += us2f((u16)q8[u]) * soe[u];
        pcr += us2f((u16)k8[u]) * qie[u];
      }
#pragma unroll
      for (int m = 1; m < 8; m <<= 1) { pcs += __shfl_xor(pcs, m, 64); pcr += __shfl_xor(pcr, m, 64); }
      float cr = pcr + cR;
      cr = fminf(1.f, fmaxf(-1.f, cr));
      const float ev = __expf(cr);
      const int col = nl ^ (d0 & 56);     // write-side XOR swizzle (proven, round 3)
#pragma unroll
      for (int u = 0; u < 8; ++u) {
        kT[(d0 + u) * 136 + col] = f2bfu(us2f((u16)k8[u]) * ev);
        vT[(d0 + u) * 136 + col] = (u16)(unsigned short)v8[u];
      }
      if ((tid & 7) == 0) {
        mob[ng] = sib[ng] * sigm(pcs + cS);
        esum += ev;
      }
    }
    __syncthreads();

    short8 af[4], bf[4];
#pragma unroll
    for (int mi = 0; mi < 4; ++mi) {
      const int row = (mi << 4) + r16;
      af[mi] = *(const short8*)&kT[row * 136 + (nf ^ (row & 56))];
    }
#pragma unroll
    for (int nj = 0; nj < 4; ++nj) {
      const int row = (nj << 4) + r16;
      bf[nj] = *(const short8*)&vT[row * 136 + (nf ^ (row & 56))];
    }
#pragma unroll
    for (int mi = 0; mi < 4; ++mi)
#pragma unroll
      for (int nj = 0; nj < 4; ++nj)
        acc[mi][nj] = __builtin_amdgcn_mfma_f32_16x16x32_bf16(af[mi], bf[nj], acc[mi][nj], 0, 0, 0);
    __syncthreads();
  }

  // cross-wave reduce (two 32-d halves through LDS) + coalesced atomics
  float* red = (float*)smem;
  float* kvb = kvm + ((size_t)bh << 12);
#pragma unroll
  for (int half = 0; half < 2; ++half) {
#pragma unroll
    for (int m2 = 0; m2 < 2; ++m2) {
      const int mi = (half << 1) + m2;
#pragma unroll
      for (int nj = 0; nj < 4; ++nj)
#pragma unroll
        for (int rg = 0; rg < 4; ++rg)
          red[(wid << 11) + (((m2 << 4) + (g << 2) + rg) << 6) + (nj << 4) + r16] = acc[mi][nj][rg];
    }
    __syncthreads();
    const int base2 = tid << 3;
#pragma unroll
    for (int u2 = 0; u2 < 2; ++u2) {
      const int o = base2 + (u2 << 2);
      float4 s0 = *(const float4*)&red[o];
      float4 s1 = *(const float4*)&red[2048 + o];
      float4 s2 = *(const float4*)&red[4096 + o];
      float4 s3 = *(const float4*)&red[6144 + o];
      s0.x += s1.x + s2.x + s3.x;
      s0.y += s1.y + s2.y + s3.y;
      s0.z += s1.z + s2.z + s3.z;
      s0.w += s1.w + s2.w + s3.w;
      const int gi = (half << 11) + o;
      atomicAdd(&kvb[gi + 0], s0.x);
      atomicAdd(&kvb[gi + 1], s0.y);
      atomicAdd(&kvb[gi + 2], s0.z);
      atomicAdd(&kvb[gi + 3], s0.w);
    }
    __syncthreads();
  }

  // sumexp: lanes 0,8,...,56 hold partials; fold within wave, 1 atomic/wave
  esum += __shfl_xor(esum, 8, 64);
  esum += __shfl_xor(esum, 16, 64);
  esum += __shfl_xor(esum, 32, 64);
  if (lane == 0) atomicAdd(&sumexp[bh], esum);
}

// ---------------- x_update = (q @ kv) * m[n] * scale -> attn [B][N][C] bf16 (MFMA) ----------------
__global__ __launch_bounds__(256) void k_xup(
    const u16* __restrict__ qkv, const float* __restrict__ kvm,
    const float* __restrict__ m_arr, const float* __restrict__ sumexp,
    u16* __restrict__ attn)
{
  const int bh = blockIdx.y;
  const int n0 = blockIdx.x << 7;
  const int b = bh / 12, h = bh % 12;
  __shared__ __align__(16) u16 qs[128 * 72];   // stride 72 elems (144B): 2-way banks, 16B aligned
  __shared__ __align__(16) u16 kvs[64 * 72];   // kv^T as [e][d] bf16
  const int tid = threadIdx.x, lane = tid & 63, wid = tid >> 6;
  const u16* qg = qkv + (size_t)b * 4096 * 2304 + (size_t)n0 * 2304 + h * 64;
#pragma unroll
  for (int i = 0; i < 4; ++i) {
    const int c = tid + (i << 8);
    const int nl = c >> 3, d0 = (c & 7) << 3;
    *(short8*)&qs[nl * 72 + d0] = *(const short8*)(qg + (size_t)nl * 2304 + d0);
  }
  const float* kvg = kvm + ((size_t)bh << 12);
#pragma unroll
  for (int i = 0; i < 4; ++i) {
    const int idx = (tid << 2) + (i << 10);
    const int d = idx >> 6, e0 = idx & 63;
    float4 vv = *(const float4*)(kvg + idx);
    kvs[(e0 + 0) * 72 + d] = f2bfu(vv.x);
    kvs[(e0 + 1) * 72 + d] = f2bfu(vv.y);
    kvs[(e0 + 2) * 72 + d] = f2bfu(vv.z);
    kvs[(e0 + 3) * 72 + d] = f2bfu(vv.w);
  }
  __syncthreads();
  const float scale = 4096.f / sumexp[bh];
  const int r16 = lane & 15, kg8 = (lane >> 4) << 3;
  f32x4 acc[2][4];
#pragma unroll
  for (int i = 0; i < 2; ++i)
#pragma unroll
    for (int j = 0; j < 4; ++j) acc[i][j] = (f32x4){0.f, 0.f, 0.f, 0.f};
#pragma unroll
  for (int kk = 0; kk < 2; ++kk) {
    short8 af[2], bfv[4];
#pragma unroll
    for (int mi = 0; mi < 2; ++mi)
      af[mi] = *(const short8*)&qs[((wid << 5) + (mi << 4) + r16) * 72 + (kk << 5) + kg8];
#pragma unroll
    for (int nj = 0; nj < 4; ++nj)
      bfv[nj] = *(const short8*)&kvs[((nj << 4) + r16) * 72 + (kk << 5) + kg8];
#pragma unroll
    for (int mi = 0; mi < 2; ++mi)
#pragma unroll
      for (int nj = 0; nj < 4; ++nj)
        acc[mi][nj] = __builtin_amdgcn_mfma_f32_16x16x32_bf16(af[mi], bfv[nj], acc[mi][nj], 0, 0, 0);
  }
#pragma unroll
  for (int mi = 0; mi < 2; ++mi) {
#pragma unroll
    for (int rg = 0; rg < 4; ++rg) {
      const int n = n0 + (wid << 5) + (mi << 4) + ((lane >> 4) << 2) + rg;
      const float mult = m_arr[((size_t)bh << 12) + n] * scale;
#pragma unroll
      for (int nj = 0; nj < 4; ++nj) {
        const int e = (nj << 4) + r16;
        attn[((size_t)(b * 4096 + n)) * 768 + (h << 6) + e] = f2bfu(acc[mi][nj][rg] * mult);
      }
    }
  }
}

extern "C" void kernel_launch(void* const* d_in, const int* in_sizes, int n_in,
                              void* d_out, int out_size, void* d_ws, size_t ws_size,
                              hipStream_t stream)
{
  (void)in_sizes; (void)n_in; (void)out_size; (void)ws_size;
  const float* x     = (const float*)d_in[0];
  const float* Wqkv  = (const float*)d_in[1];
  const float* bqkv  = (const float*)d_in[2];
  const float* Wproj = (const float*)d_in[3];
  const float* bproj = (const float*)d_in[4];
  float* out = (float*)d_out;

  char* ws = (char*)d_ws;
  size_t off = 0;
  auto alloc = [&](size_t bytes) -> char* {
    char* p = ws + off;
    off += (bytes + 255) & ~(size_t)255;
    return p;
  };
  u16* qkv  = (u16*)alloc(150994944);      // [32768][2304] bf16 flat (q|k|v)
  u16* xbf  = (u16*)alloc(50331648);       // x bf16; reused as attn output
  u16* WqT  = (u16*)alloc(3538944);        // [2304][768] bf16
  u16* WpT  = (u16*)alloc(1179648);        // [768][768] bf16
  float* si = (float*)alloc(1572864);      // [B*H][N]
  float* mb = (float*)alloc(1572864);      // si * sink_allocation
  char* zbase = ws + off;
  float* qsum   = (float*)alloc(24576);
  float* ksum   = (float*)alloc(24576);
  float* qsi    = (float*)alloc(24576);
  float* kso    = (float*)alloc(24576);
  float* sumexp = (float*)alloc(512);
  float* kvm    = (float*)alloc(1572864);  // [B*H][64 d][64 e] f32
  const size_t zbytes = (size_t)((ws + off) - zbase);

  hipMemsetAsync(zbase, 0, zbytes, stream);
  k_cvt_x<<<24576, 256, 0, stream>>>(x, xbf);
  k_transpose<<<dim3(72, 24), 256, 0, stream>>>(Wqkv, WqT, 768, 2304);
  k_transpose<<<dim3(24, 24), 256, 0, stream>>>(Wproj, WpT, 768, 768);
  k_gemm<0><<<dim3(9, 128), 512, 0, stream>>>(xbf, WqT, bqkv, qkv, qsum, ksum, nullptr);
  k_flow1<<<768, 256, 0, stream>>>(qkv, qsum, ksum, si, qsi, kso);
  k_fkv<<<768, 256, 0, stream>>>(qkv, qsi, kso, si, mb, sumexp, kvm);
  k_xup<<<dim3(32, 96), 256, 0, stream>>>(qkv, kvm, mb, sumexp, xbf);
  k_gemm<1><<<dim3(3, 128), 512, 0, stream>>>(xbf, WpT, bproj, nullptr, nullptr, nullptr, out);
}

// Round 10
// 411.747 us; speedup vs baseline: 1.0250x; 1.0006x over previous
//
#include <hip/hip_runtime.h>
#include <stdint.h>

#define EPSF 1e-6f

typedef unsigned short u16;
typedef __attribute__((ext_vector_type(8))) short short8;
typedef __attribute__((ext_vector_type(4))) float f32x4;

__device__ __forceinline__ float us2f(u16 u) {
  union { float f; unsigned int i; } c; c.i = ((unsigned int)u) << 16; return c.f;
}
__device__ __forceinline__ u16 f2bfu(float f) {
  union { float f; unsigned int i; } c; c.f = f;
  unsigned int i = c.i;
  return (u16)((i + 0x7FFFu + ((i >> 16) & 1u)) >> 16);
}
__device__ __forceinline__ float sigm(float x) { return 1.f / (1.f + __expf(-x)); }

typedef __attribute__((address_space(3))) unsigned int lds_u32;
typedef const __attribute__((address_space(1))) unsigned int glb_u32;
__device__ __forceinline__ void gl_lds16(const u16* g, u16* l) {
  __builtin_amdgcn_global_load_lds((glb_u32*)g, (lds_u32*)l, 16, 0, 0);
}

// ---------------- convert x (f32 -> bf16), 4 elems/thread ----------------
__global__ void k_cvt_x(const float* __restrict__ in, u16* __restrict__ out) {
  const int i = blockIdx.x * 256 + threadIdx.x;
  float4 v = ((const float4*)in)[i];
  ushort4 o;
  o.x = f2bfu(v.x); o.y = f2bfu(v.y); o.z = f2bfu(v.z); o.w = f2bfu(v.w);
  ((ushort4*)out)[i] = o;
}

// ---------------- transpose + convert: in f32 [R][C] -> out bf16 [C][R] ----------------
__global__ void k_transpose(const float* __restrict__ in, u16* __restrict__ out, int R, int C) {
  __shared__ float tile[32][33];
  const int tx = threadIdx.x & 31, ty = threadIdx.x >> 5;  // 32x8
  const int c0 = blockIdx.x << 5, r0 = blockIdx.y << 5;
  for (int i = ty; i < 32; i += 8) tile[i][tx] = in[(size_t)(r0 + i) * C + c0 + tx];
  __syncthreads();
  for (int i = ty; i < 32; i += 8) out[(size_t)(c0 + i) * R + r0 + tx] = f2bfu(tile[tx][i]);
}

// ---------------- GEMM: 256x256 tile, 8 waves, BK=64, m201-style 4-phase/tile ----------------
// 12 K-tiles. LDS = 8 unit-slots x 16KB (A-half0/A-half1/B-half0/B-half1 per tile, 2-tile dbuf).
// Per tile, 4 phases: {ds_read A quadrant (+B at p0) | stage 2 next-tile units (p0,p1) |
//   barrier | lgkmcnt(0) | setprio(1) 16 MFMA setprio(0) | [p3: vmcnt(0), latency-covered] | barrier}
// Chunk-XOR swizzle keyed on row&7 within 128B rows; pre-swizzled global source.
// MODE 0: flat qkv store (sigmoid q/k) + fused qsum/ksum. MODE 1: proj sigmoid(2x) f32 store.
template <int MODE>
__global__ __launch_bounds__(512, 1) void k_gemm(
    const u16* __restrict__ A, const u16* __restrict__ BT,
    const float* __restrict__ bias,
    u16* __restrict__ qkvo, float* __restrict__ qsum, float* __restrict__ ksum,
    float* __restrict__ outf)
{
  __shared__ __align__(16) u16 smem[65536];  // 128 KB = 8 x 8192 elems
  const int tid = threadIdx.x;
  const int lane = tid & 63;
  const int wid = tid >> 6;           // 0..7
  const int wm = wid >> 2, wn = wid & 3;
  // bijective XCD swizzle (nwg % 8 == 0 for both grids)
  const int nx = gridDim.x;
  int lid = blockIdx.y * nx + blockIdx.x;
  const int q8 = (nx * gridDim.y) >> 3;
  lid = (lid & 7) * q8 + (lid >> 3);
  const int m0 = (lid / nx) << 8;
  const int n0 = (lid % nx) << 8;

  // ---- staging map: thread covers chunks {tid, tid+512} of each 16KB unit ----
  // chunk_id = l*512+tid -> row = l*64 + (tid>>3), sc = tid&7; global chunk gc = sc ^ (row&7)
  const int rowL0 = tid >> 3;
  const int gc = (tid & 7) ^ (rowL0 & 7);
  const u16* gA = A  + (size_t)(m0 + rowL0) * 768 + (gc << 3);
  const u16* gB = BT + (size_t)(n0 + rowL0) * 768 + (gc << 3);

  // ---- read map ----
  const int r16 = lane & 15;
  const int sgrp = lane >> 4;
  const int xk = r16 & 7;
  const int coff0 = ((sgrp) ^ xk) << 3;            // kslot 0 chunk byte/2 offset (elems)
  const int coff1 = ((4 + sgrp) ^ xk) << 3;        // kslot 1
  const int bbase = ((wn & 1) << 6) + r16;         // B row base within its half

  f32x4 acc[8][4];
#pragma unroll
  for (int i = 0; i < 8; ++i)
#pragma unroll
    for (int j = 0; j < 4; ++j) acc[i][j] = (f32x4){0.f, 0.f, 0.f, 0.f};

#define STAGEU(tt, y)                                                         \
  do {                                                                        \
    u16* dst = &smem[(((((tt) & 1) << 2) | (y)) << 13) + (tid << 3)];         \
    const u16* s = (((y) < 2) ? gA + (size_t)(y) * 98304                      \
                              : gB + (size_t)((y) - 2) * 98304) + (tt) * 64;  \
    gl_lds16(s, dst);                                                         \
    gl_lds16(s + 49152, dst + 4096);                                          \
  } while (0)

#define RDA(mi, co) (*(const short8*)(pa + ((((mi) << 4) + r16) << 6) + (co)))
#define RDB(nj, co) (*(const short8*)(pb + ((bbase + ((nj) << 4)) << 6) + (co)))

#define MFMA16(P, A00, A01, A10, A11)                                                               \
  do {                                                                                              \
    acc[2*(P)  ][0] = __builtin_amdgcn_mfma_f32_16x16x32_bf16(A00, bf[0][0], acc[2*(P)  ][0],0,0,0);\
    acc[2*(P)  ][1] = __builtin_amdgcn_mfma_f32_16x16x32_bf16(A00, bf[1][0], acc[2*(P)  ][1],0,0,0);\
    acc[2*(P)  ][2] = __builtin_amdgcn_mfma_f32_16x16x32_bf16(A00, bf[2][0], acc[2*(P)  ][2],0,0,0);\
    acc[2*(P)  ][3] = __builtin_amdgcn_mfma_f32_16x16x32_bf16(A00, bf[3][0], acc[2*(P)  ][3],0,0,0);\
    acc[2*(P)+1][0] = __builtin_amdgcn_mfma_f32_16x16x32_bf16(A10, bf[0][0], acc[2*(P)+1][0],0,0,0);\
    acc[2*(P)+1][1] = __builtin_amdgcn_mfma_f32_16x16x32_bf16(A10, bf[1][0], acc[2*(P)+1][1],0,0,0);\
    acc[2*(P)+1][2] = __builtin_amdgcn_mfma_f32_16x16x32_bf16(A10, bf[2][0], acc[2*(P)+1][2],0,0,0);\
    acc[2*(P)+1][3] = __builtin_amdgcn_mfma_f32_16x16x32_bf16(A10, bf[3][0], acc[2*(P)+1][3],0,0,0);\
    acc[2*(P)  ][0] = __builtin_amdgcn_mfma_f32_16x16x32_bf16(A01, bf[0][1], acc[2*(P)  ][0],0,0,0);\
    acc[2*(P)  ][1] = __builtin_amdgcn_mfma_f32_16x16x32_bf16(A01, bf[1][1], acc[2*(P)  ][1],0,0,0);\
    acc[2*(P)  ][2] = __builtin_amdgcn_mfma_f32_16x16x32_bf16(A01, bf[2][1], acc[2*(P)  ][2],0,0,0);\
    acc[2*(P)  ][3] = __builtin_amdgcn_mfma_f32_16x16x32_bf16(A01, bf[3][1], acc[2*(P)  ][3],0,0,0);\
    acc[2*(P)+1][0] = __builtin_amdgcn_mfma_f32_16x16x32_bf16(A11, bf[0][1], acc[2*(P)+1][0],0,0,0);\
    acc[2*(P)+1][1] = __builtin_amdgcn_mfma_f32_16x16x32_bf16(A11, bf[1][1], acc[2*(P)+1][1],0,0,0);\
    acc[2*(P)+1][2] = __builtin_amdgcn_mfma_f32_16x16x32_bf16(A11, bf[2][1], acc[2*(P)+1][2],0,0,0);\
    acc[2*(P)+1][3] = __builtin_amdgcn_mfma_f32_16x16x32_bf16(A11, bf[3][1], acc[2*(P)+1][3],0,0,0);\
  } while (0)

#define PH_SYNC_PRE()                                          \
    __builtin_amdgcn_s_barrier();                              \
    asm volatile("s_waitcnt lgkmcnt(0)" ::: "memory");         \
    __builtin_amdgcn_sched_barrier(0);                         \
    __builtin_amdgcn_s_setprio(1)

#define PH_SYNC_POST()                                         \
    __builtin_amdgcn_s_setprio(0);                             \
    __builtin_amdgcn_sched_barrier(0);                         \
    __builtin_amdgcn_s_barrier()

  // prologue: stage tile 0 fully, drain, barrier
  STAGEU(0, 0); STAGEU(0, 1); STAGEU(0, 2); STAGEU(0, 3);
  asm volatile("s_waitcnt vmcnt(0)" ::: "memory");
  __builtin_amdgcn_s_barrier();

  for (int t = 0; t < 12; ++t) {
    const u16* pa = &smem[((((t & 1) << 2) | wm) << 13)];
    const u16* pb = &smem[((((t & 1) << 2) | (2 + (wn >> 1))) << 13)];
    short8 bf[4][2];
    // ---- phase 0: B frags (8) + A rows 0-1; stage next-tile A halves ----
    bf[0][0] = RDB(0, coff0); bf[0][1] = RDB(0, coff1);
    bf[1][0] = RDB(1, coff0); bf[1][1] = RDB(1, coff1);
    bf[2][0] = RDB(2, coff0); bf[2][1] = RDB(2, coff1);
    bf[3][0] = RDB(3, coff0); bf[3][1] = RDB(3, coff1);
    short8 a00 = RDA(0, coff0), a01 = RDA(0, coff1);
    short8 a10 = RDA(1, coff0), a11 = RDA(1, coff1);
    if (t < 11) { STAGEU(t + 1, 0); STAGEU(t + 1, 1); }
    PH_SYNC_PRE();
    MFMA16(0, a00, a01, a10, a11);
    PH_SYNC_POST();
    // ---- phase 1: A rows 2-3; stage next-tile B halves ----
    a00 = RDA(2, coff0); a01 = RDA(2, coff1);
    a10 = RDA(3, coff0); a11 = RDA(3, coff1);
    if (t < 11) { STAGEU(t + 1, 2); STAGEU(t + 1, 3); }
    PH_SYNC_PRE();
    MFMA16(1, a00, a01, a10, a11);
    PH_SYNC_POST();
    // ---- phase 2: A rows 4-5 ----
    a00 = RDA(4, coff0); a01 = RDA(4, coff1);
    a10 = RDA(5, coff0); a11 = RDA(5, coff1);
    PH_SYNC_PRE();
    MFMA16(2, a00, a01, a10, a11);
    PH_SYNC_POST();
    // ---- phase 3: A rows 6-7; end-of-tile drain (latency-covered) ----
    a00 = RDA(6, coff0); a01 = RDA(6, coff1);
    a10 = RDA(7, coff0); a11 = RDA(7, coff1);
    PH_SYNC_PRE();
    MFMA16(3, a00, a01, a10, a11);
    __builtin_amdgcn_s_setprio(0);
    __builtin_amdgcn_sched_barrier(0);
    asm volatile("s_waitcnt vmcnt(0)" ::: "memory");  // next tile landed (issued 2-3 phases ago)
    __builtin_amdgcn_s_barrier();
  }
#undef PH_SYNC_PRE
#undef PH_SYNC_POST
#undef MFMA16
#undef RDA
#undef RDB
#undef STAGEU

  if (MODE == 0) {
    const int colc = n0 + (wn << 6);        // wave's 64-col window base
    const bool sg = (colc < 1536);          // uniform per wave: q/k vs v
    float jsum[4] = {0.f, 0.f, 0.f, 0.f};
#pragma unroll
    for (int mi = 0; mi < 8; ++mi) {
      const int rowb = m0 + (wm << 7) + (mi << 4) + ((lane >> 4) << 2);
#pragma unroll
      for (int nj = 0; nj < 4; ++nj) {
        const int col = colc + (nj << 4) + r16;
        const float bcol = bias[col];
        if (sg) {
#pragma unroll
          for (int rg = 0; rg < 4; ++rg) {
            const float val = sigm(acc[mi][nj][rg] + bcol);
            jsum[nj] += val;
            qkvo[(size_t)(rowb + rg) * 2304 + col] = f2bfu(val);
          }
        } else {
#pragma unroll
          for (int rg = 0; rg < 4; ++rg)
            qkvo[(size_t)(rowb + rg) * 2304 + col] = f2bfu(acc[mi][nj][rg] + bcol);
        }
      }
    }
    if (sg) {
#pragma unroll
      for (int nj = 0; nj < 4; ++nj) {
        jsum[nj] += __shfl_xor(jsum[nj], 16, 64);
        jsum[nj] += __shfl_xor(jsum[nj], 32, 64);
      }
      if (lane < 16) {
        const int b12 = (m0 >> 12) * 12;
        float* sdst = (colc >= 768) ? ksum : qsum;
        const int cb = (colc >= 768) ? colc - 768 : colc;  // 0..767 = h*64+d
#pragma unroll
        for (int nj = 0; nj < 4; ++nj)
          atomicAdd(&sdst[(b12 << 6) + cb + (nj << 4) + r16], jsum[nj]);
      }
    }
  } else {
#pragma unroll
    for (int mi = 0; mi < 8; ++mi) {
      const int rowb = m0 + (wm << 7) + (mi << 4) + ((lane >> 4) << 2);
#pragma unroll
      for (int nj = 0; nj < 4; ++nj) {
        const int col = n0 + (wn << 6) + (nj << 4) + r16;
        const float bcol = bias[col];
#pragma unroll
        for (int rg = 0; rg < 4; ++rg)
          outf[(size_t)(rowb + rg) * 768 + col] = sigm(2.f * (acc[mi][nj][rg] + bcol));
      }
    }
  }
}

// ---------------- si/so + qsi/kso: 8-lane groups, 16B loads (fkv-pattern) ----------------
__global__ __launch_bounds__(256) void k_flow1(
    const u16* __restrict__ qkv,
    const float* __restrict__ qsum, const float* __restrict__ ksum,
    float* __restrict__ si_out, float* __restrict__ qsi, float* __restrict__ kso)
{
  const int bh = blockIdx.x >> 3, sp = blockIdx.x & 7;
  const int tid = threadIdx.x;
  const int grp = tid >> 3;            // 0..31 (row group)
  const int d0 = (tid & 7) << 3;       // 8-elem d-slice
  const u16* base = qkv + (size_t)(bh / 12) * 4096 * 2304 + (bh % 12) * 64;

  float ke[8], qe[8];
#pragma unroll
  for (int u = 0; u < 8; ++u) {
    ke[u] = ksum[(bh << 6) + d0 + u] + EPSF;
    qe[u] = qsum[(bh << 6) + d0 + u] + EPSF;
  }
  float Sk = 0.f, Sq = 0.f;
#pragma unroll
  for (int u = 0; u < 8; ++u) { Sk += ke[u]; Sq += qe[u]; }
#pragma unroll
  for (int m = 1; m < 8; m <<= 1) { Sk += __shfl_xor(Sk, m, 64); Sq += __shfl_xor(Sq, m, 64); }
  const float cK = EPSF * Sk + EPSF;
  const float cQ = EPSF * Sq + EPSF;

  float aq[8], ak[8];
#pragma unroll
  for (int u = 0; u < 8; ++u) { aq[u] = 0.f; ak[u] = 0.f; }

  const int nbase = sp << 9;
  for (int it = 0; it < 16; ++it) {
    const int n = nbase + (it << 5) + grp;
    const u16* rp = base + (size_t)n * 2304 + d0;
    short8 q8 = *(const short8*)(rp);
    short8 k8 = *(const short8*)(rp + 768);
    float dq = 0.f, dk = 0.f;
#pragma unroll
    for (int u = 0; u < 8; ++u) {
      dq += us2f((u16)q8[u]) * ke[u];
      dk += us2f((u16)k8[u]) * qe[u];
    }
#pragma unroll
    for (int m = 1; m < 8; m <<= 1) { dq += __shfl_xor(dq, m, 64); dk += __shfl_xor(dk, m, 64); }
    const float si = 1.f / (dq + cK);
    const float so = 1.f / (dk + cQ);
    if ((tid & 7) == 0) si_out[(bh << 12) + n] = si;
#pragma unroll
    for (int u = 0; u < 8; ++u) {
      aq[u] += us2f((u16)q8[u]) * si;
      ak[u] += us2f((u16)k8[u]) * so;
    }
  }
  __shared__ float redq[32][68];
  __shared__ float redk[32][68];
#pragma unroll
  for (int u = 0; u < 8; ++u) { redq[grp][d0 + u] = aq[u]; redk[grp][d0 + u] = ak[u]; }
  __syncthreads();
  if (tid < 128) {
    const int which = tid >> 6, d = tid & 63;
    float s = 0.f;
    if (which == 0) {
#pragma unroll
      for (int g = 0; g < 32; ++g) s += redq[g][d];
      atomicAdd(&qsi[(bh << 6) + d], s);
    } else {
#pragma unroll
      for (int g = 0; g < 32; ++g) s += redk[g][d];
      atomicAdd(&kso[(bh << 6) + d], s);
    }
  }
}

// ---------------- fused flow2 + kv (MFMA): e/m/sumexp inline, kvm[d][e] accumulate ----------------
__global__ __launch_bounds__(256) void k_fkv(
    const u16* __restrict__ qkv,
    const float* __restrict__ qsi, const float* __restrict__ kso,
    const float* __restrict__ si_in,
    float* __restrict__ mo, float* __restrict__ sumexp, float* __restrict__ kvm)
{
  __shared__ __align__(16) u16 smem[2 * 64 * 136];  // 34816 B; reused as f32 reduce buf
  u16* kT = smem;
  u16* vT = smem + 64 * 136;
  const int tid = threadIdx.x;
  const int bh = blockIdx.x >> 3, sp = blockIdx.x & 7;
  const int lane = tid & 63, wid = tid >> 6;
  const int r16 = lane & 15, g = lane >> 4;
  const u16* base = qkv + (size_t)(bh / 12) * 4096 * 2304 + (bh % 12) * 64;
  const float* sib = si_in + ((size_t)bh << 12);
  float* mob = mo + ((size_t)bh << 12);

  // per-thread d-slice (constant across stages/iters)
  const int d0 = (tid & 7) << 3;
  float qie[8], soe[8];
#pragma unroll
  for (int u = 0; u < 8; ++u) {
    qie[u] = qsi[(bh << 6) + d0 + u] + EPSF;
    soe[u] = kso[(bh << 6) + d0 + u] + EPSF;
  }
  // block-uniform eps terms: cR = eps*sum(qsi+eps)+eps, cS = eps*sum(kso+eps)+eps
  float Sq = qsi[(bh << 6) + lane] + EPSF;
  float Sk = kso[(bh << 6) + lane] + EPSF;
#pragma unroll
  for (int m = 1; m < 64; m <<= 1) { Sq += __shfl_xor(Sq, m, 64); Sk += __shfl_xor(Sk, m, 64); }
  const float cR = EPSF * Sq + EPSF;
  const float cS = EPSF * Sk + EPSF;

  f32x4 acc[4][4];
#pragma unroll
  for (int i = 0; i < 4; ++i)
#pragma unroll
    for (int j = 0; j < 4; ++j) acc[i][j] = (f32x4){0.f, 0.f, 0.f, 0.f};

  const int nf = (wid << 5) + (g << 3);  // wave n-window + lane-group k offset
  float esum = 0.f;

  for (int st = 0; st < 4; ++st) {
    const int nst = (sp << 9) + (st << 7);
#pragma unroll
    for (int i = 0; i < 4; ++i) {
      const int c = tid + (i << 8);
      const int nl = c >> 3;              // 0..127
      const int ng = nst + nl;
      const u16* rp = base + (size_t)ng * 2304 + d0;
      short8 q8 = *(const short8*)(rp);
      short8 k8 = *(const short8*)(rp + 768);
      short8 v8 = *(const short8*)(rp + 1536);
      float pcs = 0.f, pcr = 0.f;
#pragma unroll
      for (int u = 0; u < 8; ++u) {
        pcs += us2f((u16)q8[u]) * soe[u];
        pcr += us2f((u16)k8[u]) * qie[u];
      }
#pragma unroll
      for (int m = 1; m < 8; m <<= 1) { pcs += __shfl_xor(pcs, m, 64); pcr += __shfl_xor(pcr, m, 64); }
      float cr = pcr + cR;
      cr = fminf(1.f, fmaxf(-1.f, cr));
      const float ev = __expf(cr);
      const int col = nl ^ (d0 & 56);     // write-side XOR swizzle (proven, round 3)
#pragma unroll
      for (int u = 0; u < 8; ++u) {
        kT[(d0 + u) * 136 + col] = f2bfu(us2f((u16)k8[u]) * ev);
        vT[(d0 + u) * 136 + col] = (u16)(unsigned short)v8[u];
      }
      if ((tid & 7) == 0) {
        mob[ng] = sib[ng] * sigm(pcs + cS);
        esum += ev;
      }
    }
    __syncthreads();

    short8 af[4], bf[4];
#pragma unroll
    for (int mi = 0; mi < 4; ++mi) {
      const int row = (mi << 4) + r16;
      af[mi] = *(const short8*)&kT[row * 136 + (nf ^ (row & 56))];
    }
#pragma unroll
    for (int nj = 0; nj < 4; ++nj) {
      const int row = (nj << 4) + r16;
      bf[nj] = *(const short8*)&vT[row * 136 + (nf ^ (row & 56))];
    }
#pragma unroll
    for (int mi = 0; mi < 4; ++mi)
#pragma unroll
      for (int nj = 0; nj < 4; ++nj)
        acc[mi][nj] = __builtin_amdgcn_mfma_f32_16x16x32_bf16(af[mi], bf[nj], acc[mi][nj], 0, 0, 0);
    __syncthreads();
  }

  // cross-wave reduce (two 32-d halves through LDS) + coalesced atomics
  float* red = (float*)smem;
  float* kvb = kvm + ((size_t)bh << 12);
#pragma unroll
  for (int half = 0; half < 2; ++half) {
#pragma unroll
    for (int m2 = 0; m2 < 2; ++m2) {
      const int mi = (half << 1) + m2;
#pragma unroll
      for (int nj = 0; nj < 4; ++nj)
#pragma unroll
        for (int rg = 0; rg < 4; ++rg)
          red[(wid << 11) + (((m2 << 4) + (g << 2) + rg) << 6) + (nj << 4) + r16] = acc[mi][nj][rg];
    }
    __syncthreads();
    const int base2 = tid << 3;
#pragma unroll
    for (int u2 = 0; u2 < 2; ++u2) {
      const int o = base2 + (u2 << 2);
      float4 s0 = *(const float4*)&red[o];
      float4 s1 = *(const float4*)&red[2048 + o];
      float4 s2 = *(const float4*)&red[4096 + o];
      float4 s3 = *(const float4*)&red[6144 + o];
      s0.x += s1.x + s2.x + s3.x;
      s0.y += s1.y + s2.y + s3.y;
      s0.z += s1.z + s2.z + s3.z;
      s0.w += s1.w + s2.w + s3.w;
      const int gi = (half << 11) + o;
      atomicAdd(&kvb[gi + 0], s0.x);
      atomicAdd(&kvb[gi + 1], s0.y);
      atomicAdd(&kvb[gi + 2], s0.z);
      atomicAdd(&kvb[gi + 3], s0.w);
    }
    __syncthreads();
  }

  // sumexp: lanes 0,8,...,56 hold partials; fold within wave, 1 atomic/wave
  esum += __shfl_xor(esum, 8, 64);
  esum += __shfl_xor(esum, 16, 64);
  esum += __shfl_xor(esum, 32, 64);
  if (lane == 0) atomicAdd(&sumexp[bh], esum);
}

// ---------------- x_update = (q @ kv) * m[n] * scale -> attn [B][N][C] bf16 (MFMA) ----------------
__global__ __launch_bounds__(256) void k_xup(
    const u16* __restrict__ qkv, const float* __restrict__ kvm,
    const float* __restrict__ m_arr, const float* __restrict__ sumexp,
    u16* __restrict__ attn)
{
  const int bh = blockIdx.y;
  const int n0 = blockIdx.x << 7;
  const int b = bh / 12, h = bh % 12;
  __shared__ __align__(16) u16 qs[128 * 72];   // stride 72 elems (144B): 2-way banks, 16B aligned
  __shared__ __align__(16) u16 kvs[64 * 72];   // kv^T as [e][d] bf16
  const int tid = threadIdx.x, lane = tid & 63, wid = tid >> 6;
  const u16* qg = qkv + (size_t)b * 4096 * 2304 + (size_t)n0 * 2304 + h * 64;
#pragma unroll
  for (int i = 0; i < 4; ++i) {
    const int c = tid + (i << 8);
    const int nl = c >> 3, d0 = (c & 7) << 3;
    *(short8*)&qs[nl * 72 + d0] = *(const short8*)(qg + (size_t)nl * 2304 + d0);
  }
  const float* kvg = kvm + ((size_t)bh << 12);
#pragma unroll
  for (int i = 0; i < 4; ++i) {
    const int idx = (tid << 2) + (i << 10);
    const int d = idx >> 6, e0 = idx & 63;
    float4 vv = *(const float4*)(kvg + idx);
    kvs[(e0 + 0) * 72 + d] = f2bfu(vv.x);
    kvs[(e0 + 1) * 72 + d] = f2bfu(vv.y);
    kvs[(e0 + 2) * 72 + d] = f2bfu(vv.z);
    kvs[(e0 + 3) * 72 + d] = f2bfu(vv.w);
  }
  __syncthreads();
  const float scale = 4096.f / sumexp[bh];
  const int r16 = lane & 15, kg8 = (lane >> 4) << 3;
  f32x4 acc[2][4];
#pragma unroll
  for (int i = 0; i < 2; ++i)
#pragma unroll
    for (int j = 0; j < 4; ++j) acc[i][j] = (f32x4){0.f, 0.f, 0.f, 0.f};
#pragma unroll
  for (int kk = 0; kk < 2; ++kk) {
    short8 af[2], bfv[4];
#pragma unroll
    for (int mi = 0; mi < 2; ++mi)
      af[mi] = *(const short8*)&qs[((wid << 5) + (mi << 4) + r16) * 72 + (kk << 5) + kg8];
#pragma unroll
    for (int nj = 0; nj < 4; ++nj)
      bfv[nj] = *(const short8*)&kvs[((nj << 4) + r16) * 72 + (kk << 5) + kg8];
#pragma unroll
    for (int mi = 0; mi < 2; ++mi)
#pragma unroll
      for (int nj = 0; nj < 4; ++nj)
        acc[mi][nj] = __builtin_amdgcn_mfma_f32_16x16x32_bf16(af[mi], bfv[nj], acc[mi][nj], 0, 0, 0);
  }
#pragma unroll
  for (int mi = 0; mi < 2; ++mi) {
#pragma unroll
    for (int rg = 0; rg < 4; ++rg) {
      const int n = n0 + (wid << 5) + (mi << 4) + ((lane >> 4) << 2) + rg;
      const float mult = m_arr[((size_t)bh << 12) + n] * scale;
#pragma unroll
      for (int nj = 0; nj < 4; ++nj) {
        const int e = (nj << 4) + r16;
        attn[((size_t)(b * 4096 + n)) * 768 + (h << 6) + e] = f2bfu(acc[mi][nj][rg] * mult);
      }
    }
  }
}

extern "C" void kernel_launch(void* const* d_in, const int* in_sizes, int n_in,
                              void* d_out, int out_size, void* d_ws, size_t ws_size,
                              hipStream_t stream)
{
  (void)in_sizes; (void)n_in; (void)out_size; (void)ws_size;
  const float* x     = (const float*)d_in[0];
  const float* Wqkv  = (const float*)d_in[1];
  const float* bqkv  = (const float*)d_in[2];
  const float* Wproj = (const float*)d_in[3];
  const float* bproj = (const float*)d_in[4];
  float* out = (float*)d_out;

  char* ws = (char*)d_ws;
  size_t off = 0;
  auto alloc = [&](size_t bytes) -> char* {
    char* p = ws + off;
    off += (bytes + 255) & ~(size_t)255;
    return p;
  };
  u16* qkv  = (u16*)alloc(150994944);      // [32768][2304] bf16 flat (q|k|v)
  u16* xbf  = (u16*)alloc(50331648);       // x bf16; reused as attn output
  u16* WqT  = (u16*)alloc(3538944);        // [2304][768] bf16
  u16* WpT  = (u16*)alloc(1179648);        // [768][768] bf16
  float* si = (float*)alloc(1572864);      // [B*H][N]
  float* mb = (float*)alloc(1572864);      // si * sink_allocation
  char* zbase = ws + off;
  float* qsum   = (float*)alloc(24576);
  float* ksum   = (float*)alloc(24576);
  float* qsi    = (float*)alloc(24576);
  float* kso    = (float*)alloc(24576);
  float* sumexp = (float*)alloc(512);
  float* kvm    = (float*)alloc(1572864);  // [B*H][64 d][64 e] f32
  const size_t zbytes = (size_t)((ws + off) - zbase);

  hipMemsetAsync(zbase, 0, zbytes, stream);
  k_cvt_x<<<24576, 256, 0, stream>>>(x, xbf);
  k_transpose<<<dim3(72, 24), 256, 0, stream>>>(Wqkv, WqT, 768, 2304);
  k_transpose<<<dim3(24, 24), 256, 0, stream>>>(Wproj, WpT, 768, 768);
  k_gemm<0><<<dim3(9, 128), 512, 0, stream>>>(xbf, WqT, bqkv, qkv, qsum, ksum, nullptr);
  k_flow1<<<768, 256, 0, stream>>>(qkv, qsum, ksum, si, qsi, kso);
  k_fkv<<<768, 256, 0, stream>>>(qkv, qsi, kso, si, mb, sumexp, kvm);
  k_xup<<<dim3(32, 96), 256, 0, stream>>>(qkv, kvm, mb, sumexp, xbf);
  k_gemm<1><<<dim3(3, 128), 512, 0, stream>>>(xbf, WpT, bproj, nullptr, nullptr, nullptr, out);
}

// Round 11
// 391.836 us; speedup vs baseline: 1.0771x; 1.0508x over previous
//
#include <hip/hip_runtime.h>
#include <stdint.h>

#define EPSF 1e-6f

typedef unsigned short u16;
typedef __attribute__((ext_vector_type(8))) short short8;
typedef __attribute__((ext_vector_type(4))) float f32x4;

__device__ __forceinline__ float us2f(u16 u) {
  union { float f; unsigned int i; } c; c.i = ((unsigned int)u) << 16; return c.f;
}
__device__ __forceinline__ u16 f2bfu(float f) {
  union { float f; unsigned int i; } c; c.f = f;
  unsigned int i = c.i;
  return (u16)((i + 0x7FFFu + ((i >> 16) & 1u)) >> 16);
}
__device__ __forceinline__ float sigm(float x) { return 1.f / (1.f + __expf(-x)); }

typedef __attribute__((address_space(3))) unsigned int lds_u32;
typedef const __attribute__((address_space(1))) unsigned int glb_u32;
__device__ __forceinline__ void gl_lds16(const u16* g, u16* l) {
  __builtin_amdgcn_global_load_lds((glb_u32*)g, (lds_u32*)l, 16, 0, 0);
}

// ---------------- fused prep: x cvt (blocks 0..24575) + W transposes ----------------
__global__ void k_prep(const float* __restrict__ x, u16* __restrict__ xbf,
                       const float* __restrict__ Wqkv, u16* __restrict__ WqT,
                       const float* __restrict__ Wproj, u16* __restrict__ WpT) {
  __shared__ float tile[32][33];
  const int b = blockIdx.x;
  if (b < 24576) {
    const int i = b * 256 + threadIdx.x;
    float4 v = ((const float4*)x)[i];
    ushort4 o;
    o.x = f2bfu(v.x); o.y = f2bfu(v.y); o.z = f2bfu(v.z); o.w = f2bfu(v.w);
    ((ushort4*)xbf)[i] = o;
    return;
  }
  const float* in; u16* out; int R, C, bx, by;
  if (b < 24576 + 1728) {
    const int id = b - 24576; in = Wqkv; out = WqT; R = 768; C = 2304; bx = id % 72; by = id / 72;
  } else {
    const int id = b - 26304; in = Wproj; out = WpT; R = 768; C = 768; bx = id % 24; by = id / 24;
  }
  const int tx = threadIdx.x & 31, ty = threadIdx.x >> 5;
  const int c0 = bx << 5, r0 = by << 5;
  for (int i = ty; i < 32; i += 8) tile[i][tx] = in[(size_t)(r0 + i) * C + c0 + tx];
  __syncthreads();
  for (int i = ty; i < 32; i += 8) out[(size_t)(c0 + i) * R + r0 + tx] = f2bfu(tile[tx][i]);
}

// ---------------- GEMM: 256x256 tile, 8 waves, BK=64, 4-phase/tile (round-10, frozen) ----------------
template <int MODE>
__global__ __launch_bounds__(512, 1) void k_gemm(
    const u16* __restrict__ A, const u16* __restrict__ BT,
    const float* __restrict__ bias,
    u16* __restrict__ qkvo, float* __restrict__ qsum, float* __restrict__ ksum,
    float* __restrict__ outf)
{
  __shared__ __align__(16) u16 smem[65536];  // 128 KB = 8 x 8192 elems
  const int tid = threadIdx.x;
  const int lane = tid & 63;
  const int wid = tid >> 6;           // 0..7
  const int wm = wid >> 2, wn = wid & 3;
  // bijective XCD swizzle (nwg % 8 == 0 for both grids)
  const int nx = gridDim.x;
  int lid = blockIdx.y * nx + blockIdx.x;
  const int q8 = (nx * gridDim.y) >> 3;
  lid = (lid & 7) * q8 + (lid >> 3);
  const int m0 = (lid / nx) << 8;
  const int n0 = (lid % nx) << 8;

  const int rowL0 = tid >> 3;
  const int gc = (tid & 7) ^ (rowL0 & 7);
  const u16* gA = A  + (size_t)(m0 + rowL0) * 768 + (gc << 3);
  const u16* gB = BT + (size_t)(n0 + rowL0) * 768 + (gc << 3);

  const int r16 = lane & 15;
  const int sgrp = lane >> 4;
  const int xk = r16 & 7;
  const int coff0 = ((sgrp) ^ xk) << 3;
  const int coff1 = ((4 + sgrp) ^ xk) << 3;
  const int bbase = ((wn & 1) << 6) + r16;

  f32x4 acc[8][4];
#pragma unroll
  for (int i = 0; i < 8; ++i)
#pragma unroll
    for (int j = 0; j < 4; ++j) acc[i][j] = (f32x4){0.f, 0.f, 0.f, 0.f};

#define STAGEU(tt, y)                                                         \
  do {                                                                        \
    u16* dst = &smem[(((((tt) & 1) << 2) | (y)) << 13) + (tid << 3)];         \
    const u16* s = (((y) < 2) ? gA + (size_t)(y) * 98304                      \
                              : gB + (size_t)((y) - 2) * 98304) + (tt) * 64;  \
    gl_lds16(s, dst);                                                         \
    gl_lds16(s + 49152, dst + 4096);                                          \
  } while (0)

#define RDA(mi, co) (*(const short8*)(pa + ((((mi) << 4) + r16) << 6) + (co)))
#define RDB(nj, co) (*(const short8*)(pb + ((bbase + ((nj) << 4)) << 6) + (co)))

#define MFMA16(P, A00, A01, A10, A11)                                                               \
  do {                                                                                              \
    acc[2*(P)  ][0] = __builtin_amdgcn_mfma_f32_16x16x32_bf16(A00, bf[0][0], acc[2*(P)  ][0],0,0,0);\
    acc[2*(P)  ][1] = __builtin_amdgcn_mfma_f32_16x16x32_bf16(A00, bf[1][0], acc[2*(P)  ][1],0,0,0);\
    acc[2*(P)  ][2] = __builtin_amdgcn_mfma_f32_16x16x32_bf16(A00, bf[2][0], acc[2*(P)  ][2],0,0,0);\
    acc[2*(P)  ][3] = __builtin_amdgcn_mfma_f32_16x16x32_bf16(A00, bf[3][0], acc[2*(P)  ][3],0,0,0);\
    acc[2*(P)+1][0] = __builtin_amdgcn_mfma_f32_16x16x32_bf16(A10, bf[0][0], acc[2*(P)+1][0],0,0,0);\
    acc[2*(P)+1][1] = __builtin_amdgcn_mfma_f32_16x16x32_bf16(A10, bf[1][0], acc[2*(P)+1][1],0,0,0);\
    acc[2*(P)+1][2] = __builtin_amdgcn_mfma_f32_16x16x32_bf16(A10, bf[2][0], acc[2*(P)+1][2],0,0,0);\
    acc[2*(P)+1][3] = __builtin_amdgcn_mfma_f32_16x16x32_bf16(A10, bf[3][0], acc[2*(P)+1][3],0,0,0);\
    acc[2*(P)  ][0] = __builtin_amdgcn_mfma_f32_16x16x32_bf16(A01, bf[0][1], acc[2*(P)  ][0],0,0,0);\
    acc[2*(P)  ][1] = __builtin_amdgcn_mfma_f32_16x16x32_bf16(A01, bf[1][1], acc[2*(P)  ][1],0,0,0);\
    acc[2*(P)  ][2] = __builtin_amdgcn_mfma_f32_16x16x32_bf16(A01, bf[2][1], acc[2*(P)  ][2],0,0,0);\
    acc[2*(P)  ][3] = __builtin_amdgcn_mfma_f32_16x16x32_bf16(A01, bf[3][1], acc[2*(P)  ][3],0,0,0);\
    acc[2*(P)+1][0] = __builtin_amdgcn_mfma_f32_16x16x32_bf16(A11, bf[0][1], acc[2*(P)+1][0],0,0,0);\
    acc[2*(P)+1][1] = __builtin_amdgcn_mfma_f32_16x16x32_bf16(A11, bf[1][1], acc[2*(P)+1][1],0,0,0);\
    acc[2*(P)+1][2] = __builtin_amdgcn_mfma_f32_16x16x32_bf16(A11, bf[2][1], acc[2*(P)+1][2],0,0,0);\
    acc[2*(P)+1][3] = __builtin_amdgcn_mfma_f32_16x16x32_bf16(A11, bf[3][1], acc[2*(P)+1][3],0,0,0);\
  } while (0)

#define PH_SYNC_PRE()                                          \
    __builtin_amdgcn_s_barrier();                              \
    asm volatile("s_waitcnt lgkmcnt(0)" ::: "memory");         \
    __builtin_amdgcn_sched_barrier(0);                         \
    __builtin_amdgcn_s_setprio(1)

#define PH_SYNC_POST()                                         \
    __builtin_amdgcn_s_setprio(0);                             \
    __builtin_amdgcn_sched_barrier(0);                         \
    __builtin_amdgcn_s_barrier()

  STAGEU(0, 0); STAGEU(0, 1); STAGEU(0, 2); STAGEU(0, 3);
  asm volatile("s_waitcnt vmcnt(0)" ::: "memory");
  __builtin_amdgcn_s_barrier();

  for (int t = 0; t < 12; ++t) {
    const u16* pa = &smem[((((t & 1) << 2) | wm) << 13)];
    const u16* pb = &smem[((((t & 1) << 2) | (2 + (wn >> 1))) << 13)];
    short8 bf[4][2];
    bf[0][0] = RDB(0, coff0); bf[0][1] = RDB(0, coff1);
    bf[1][0] = RDB(1, coff0); bf[1][1] = RDB(1, coff1);
    bf[2][0] = RDB(2, coff0); bf[2][1] = RDB(2, coff1);
    bf[3][0] = RDB(3, coff0); bf[3][1] = RDB(3, coff1);
    short8 a00 = RDA(0, coff0), a01 = RDA(0, coff1);
    short8 a10 = RDA(1, coff0), a11 = RDA(1, coff1);
    if (t < 11) { STAGEU(t + 1, 0); STAGEU(t + 1, 1); }
    PH_SYNC_PRE();
    MFMA16(0, a00, a01, a10, a11);
    PH_SYNC_POST();
    a00 = RDA(2, coff0); a01 = RDA(2, coff1);
    a10 = RDA(3, coff0); a11 = RDA(3, coff1);
    if (t < 11) { STAGEU(t + 1, 2); STAGEU(t + 1, 3); }
    PH_SYNC_PRE();
    MFMA16(1, a00, a01, a10, a11);
    PH_SYNC_POST();
    a00 = RDA(4, coff0); a01 = RDA(4, coff1);
    a10 = RDA(5, coff0); a11 = RDA(5, coff1);
    PH_SYNC_PRE();
    MFMA16(2, a00, a01, a10, a11);
    PH_SYNC_POST();
    a00 = RDA(6, coff0); a01 = RDA(6, coff1);
    a10 = RDA(7, coff0); a11 = RDA(7, coff1);
    PH_SYNC_PRE();
    MFMA16(3, a00, a01, a10, a11);
    __builtin_amdgcn_s_setprio(0);
    __builtin_amdgcn_sched_barrier(0);
    asm volatile("s_waitcnt vmcnt(0)" ::: "memory");
    __builtin_amdgcn_s_barrier();
  }
#undef PH_SYNC_PRE
#undef PH_SYNC_POST
#undef MFMA16
#undef RDA
#undef RDB
#undef STAGEU

  if (MODE == 0) {
    const int colc = n0 + (wn << 6);
    const bool sg = (colc < 1536);
    float jsum[4] = {0.f, 0.f, 0.f, 0.f};
#pragma unroll
    for (int mi = 0; mi < 8; ++mi) {
      const int rowb = m0 + (wm << 7) + (mi << 4) + ((lane >> 4) << 2);
#pragma unroll
      for (int nj = 0; nj < 4; ++nj) {
        const int col = colc + (nj << 4) + r16;
        const float bcol = bias[col];
        if (sg) {
#pragma unroll
          for (int rg = 0; rg < 4; ++rg) {
            const float val = sigm(acc[mi][nj][rg] + bcol);
            jsum[nj] += val;
            qkvo[(size_t)(rowb + rg) * 2304 + col] = f2bfu(val);
          }
        } else {
#pragma unroll
          for (int rg = 0; rg < 4; ++rg)
            qkvo[(size_t)(rowb + rg) * 2304 + col] = f2bfu(acc[mi][nj][rg] + bcol);
        }
      }
    }
    if (sg) {
#pragma unroll
      for (int nj = 0; nj < 4; ++nj) {
        jsum[nj] += __shfl_xor(jsum[nj], 16, 64);
        jsum[nj] += __shfl_xor(jsum[nj], 32, 64);
      }
      if (lane < 16) {
        const int b12 = (m0 >> 12) * 12;
        float* sdst = (colc >= 768) ? ksum : qsum;
        const int cb = (colc >= 768) ? colc - 768 : colc;
#pragma unroll
        for (int nj = 0; nj < 4; ++nj)
          atomicAdd(&sdst[(b12 << 6) + cb + (nj << 4) + r16], jsum[nj]);
      }
    }
  } else {
#pragma unroll
    for (int mi = 0; mi < 8; ++mi) {
      const int rowb = m0 + (wm << 7) + (mi << 4) + ((lane >> 4) << 2);
#pragma unroll
      for (int nj = 0; nj < 4; ++nj) {
        const int col = n0 + (wn << 6) + (nj << 4) + r16;
        const float bcol = bias[col];
#pragma unroll
        for (int rg = 0; rg < 4; ++rg)
          outf[(size_t)(rowb + rg) * 768 + col] = sigm(2.f * (acc[mi][nj][rg] + bcol));
      }
    }
  }
}

// ---------------- si/so + qsi/kso: 8-lane groups, 16B loads ----------------
__global__ __launch_bounds__(256) void k_flow1(
    const u16* __restrict__ qkv,
    const float* __restrict__ qsum, const float* __restrict__ ksum,
    float* __restrict__ si_out, float* __restrict__ qsi, float* __restrict__ kso)
{
  const int bh = blockIdx.x >> 3, sp = blockIdx.x & 7;
  const int tid = threadIdx.x;
  const int grp = tid >> 3;
  const int d0 = (tid & 7) << 3;
  const u16* base = qkv + (size_t)(bh / 12) * 4096 * 2304 + (bh % 12) * 64;

  float ke[8], qe[8];
#pragma unroll
  for (int u = 0; u < 8; ++u) {
    ke[u] = ksum[(bh << 6) + d0 + u] + EPSF;
    qe[u] = qsum[(bh << 6) + d0 + u] + EPSF;
  }
  float Sk = 0.f, Sq = 0.f;
#pragma unroll
  for (int u = 0; u < 8; ++u) { Sk += ke[u]; Sq += qe[u]; }
#pragma unroll
  for (int m = 1; m < 8; m <<= 1) { Sk += __shfl_xor(Sk, m, 64); Sq += __shfl_xor(Sq, m, 64); }
  const float cK = EPSF * Sk + EPSF;
  const float cQ = EPSF * Sq + EPSF;

  float aq[8], ak[8];
#pragma unroll
  for (int u = 0; u < 8; ++u) { aq[u] = 0.f; ak[u] = 0.f; }

  const int nbase = sp << 9;
  for (int it = 0; it < 16; ++it) {
    const int n = nbase + (it << 5) + grp;
    const u16* rp = base + (size_t)n * 2304 + d0;
    short8 q8 = *(const short8*)(rp);
    short8 k8 = *(const short8*)(rp + 768);
    float dq = 0.f, dk = 0.f;
#pragma unroll
    for (int u = 0; u < 8; ++u) {
      dq += us2f((u16)q8[u]) * ke[u];
      dk += us2f((u16)k8[u]) * qe[u];
    }
#pragma unroll
    for (int m = 1; m < 8; m <<= 1) { dq += __shfl_xor(dq, m, 64); dk += __shfl_xor(dk, m, 64); }
    const float si = 1.f / (dq + cK);
    const float so = 1.f / (dk + cQ);
    if ((tid & 7) == 0) si_out[(bh << 12) + n] = si;
#pragma unroll
    for (int u = 0; u < 8; ++u) {
      aq[u] += us2f((u16)q8[u]) * si;
      ak[u] += us2f((u16)k8[u]) * so;
    }
  }
  __shared__ float redq[32][68];
  __shared__ float redk[32][68];
#pragma unroll
  for (int u = 0; u < 8; ++u) { redq[grp][d0 + u] = aq[u]; redk[grp][d0 + u] = ak[u]; }
  __syncthreads();
  if (tid < 128) {
    const int which = tid >> 6, d = tid & 63;
    float s = 0.f;
    if (which == 0) {
#pragma unroll
      for (int g = 0; g < 32; ++g) s += redq[g][d];
      atomicAdd(&qsi[(bh << 6) + d], s);
    } else {
#pragma unroll
      for (int g = 0; g < 32; ++g) s += redk[g][d];
      atomicAdd(&kso[(bh << 6) + d], s);
    }
  }
}

// ---------------- fused kv (MFMA): e/sumexp inline, kvm[d][e] accumulate ----------------
// (pcs / m moved to k_xup, which reads the same q rows anyway)
__global__ __launch_bounds__(256) void k_fkv(
    const u16* __restrict__ qkv,
    const float* __restrict__ qsi,
    float* __restrict__ sumexp, float* __restrict__ kvm)
{
  __shared__ __align__(16) u16 smem[2 * 64 * 136];  // 34816 B; reused as f32 reduce buf
  u16* kT = smem;
  u16* vT = smem + 64 * 136;
  const int tid = threadIdx.x;
  const int bh = blockIdx.x >> 3, sp = blockIdx.x & 7;
  const int lane = tid & 63, wid = tid >> 6;
  const int r16 = lane & 15, g = lane >> 4;
  const u16* base = qkv + (size_t)(bh / 12) * 4096 * 2304 + (bh % 12) * 64;

  const int d0 = (tid & 7) << 3;
  float qie[8];
#pragma unroll
  for (int u = 0; u < 8; ++u) qie[u] = qsi[(bh << 6) + d0 + u] + EPSF;
  float Sq = qsi[(bh << 6) + lane] + EPSF;
#pragma unroll
  for (int m = 1; m < 64; m <<= 1) Sq += __shfl_xor(Sq, m, 64);
  const float cR = EPSF * Sq + EPSF;

  f32x4 acc[4][4];
#pragma unroll
  for (int i = 0; i < 4; ++i)
#pragma unroll
    for (int j = 0; j < 4; ++j) acc[i][j] = (f32x4){0.f, 0.f, 0.f, 0.f};

  const int nf = (wid << 5) + (g << 3);
  float esum = 0.f;

  for (int st = 0; st < 4; ++st) {
    const int nst = (sp << 9) + (st << 7);
#pragma unroll
    for (int i = 0; i < 4; ++i) {
      const int c = tid + (i << 8);
      const int nl = c >> 3;
      const int ng = nst + nl;
      const u16* rp = base + (size_t)ng * 2304 + d0;
      short8 k8 = *(const short8*)(rp + 768);
      short8 v8 = *(const short8*)(rp + 1536);
      float pcr = 0.f;
#pragma unroll
      for (int u = 0; u < 8; ++u) pcr += us2f((u16)k8[u]) * qie[u];
#pragma unroll
      for (int m = 1; m < 8; m <<= 1) pcr += __shfl_xor(pcr, m, 64);
      float cr = pcr + cR;
      cr = fminf(1.f, fmaxf(-1.f, cr));
      const float ev = __expf(cr);
      const int col = nl ^ (d0 & 56);
#pragma unroll
      for (int u = 0; u < 8; ++u) {
        kT[(d0 + u) * 136 + col] = f2bfu(us2f((u16)k8[u]) * ev);
        vT[(d0 + u) * 136 + col] = (u16)(unsigned short)v8[u];
      }
      if ((tid & 7) == 0) esum += ev;
    }
    __syncthreads();

    short8 af[4], bf[4];
#pragma unroll
    for (int mi = 0; mi < 4; ++mi) {
      const int row = (mi << 4) + r16;
      af[mi] = *(const short8*)&kT[row * 136 + (nf ^ (row & 56))];
    }
#pragma unroll
    for (int nj = 0; nj < 4; ++nj) {
      const int row = (nj << 4) + r16;
      bf[nj] = *(const short8*)&vT[row * 136 + (nf ^ (row & 56))];
    }
#pragma unroll
    for (int mi = 0; mi < 4; ++mi)
#pragma unroll
      for (int nj = 0; nj < 4; ++nj)
        acc[mi][nj] = __builtin_amdgcn_mfma_f32_16x16x32_bf16(af[mi], bf[nj], acc[mi][nj], 0, 0, 0);
    __syncthreads();
  }

  // cross-wave reduce (two 32-d halves through LDS) + coalesced atomics
  float* red = (float*)smem;
  float* kvb = kvm + ((size_t)bh << 12);
#pragma unroll
  for (int half = 0; half < 2; ++half) {
#pragma unroll
    for (int m2 = 0; m2 < 2; ++m2) {
      const int mi = (half << 1) + m2;
#pragma unroll
      for (int nj = 0; nj < 4; ++nj)
#pragma unroll
        for (int rg = 0; rg < 4; ++rg)
          red[(wid << 11) + (((m2 << 4) + (g << 2) + rg) << 6) + (nj << 4) + r16] = acc[mi][nj][rg];
    }
    __syncthreads();
    const int base2 = tid << 3;
#pragma unroll
    for (int u2 = 0; u2 < 2; ++u2) {
      const int o = base2 + (u2 << 2);
      float4 s0 = *(const float4*)&red[o];
      float4 s1 = *(const float4*)&red[2048 + o];
      float4 s2 = *(const float4*)&red[4096 + o];
      float4 s3 = *(const float4*)&red[6144 + o];
      s0.x += s1.x + s2.x + s3.x;
      s0.y += s1.y + s2.y + s3.y;
      s0.z += s1.z + s2.z + s3.z;
      s0.w += s1.w + s2.w + s3.w;
      const int gi = (half << 11) + o;
      atomicAdd(&kvb[gi + 0], s0.x);
      atomicAdd(&kvb[gi + 1], s0.y);
      atomicAdd(&kvb[gi + 2], s0.z);
      atomicAdd(&kvb[gi + 3], s0.w);
    }
    __syncthreads();
  }

  esum += __shfl_xor(esum, 8, 64);
  esum += __shfl_xor(esum, 16, 64);
  esum += __shfl_xor(esum, 32, 64);
  if (lane == 0) atomicAdd(&sumexp[bh], esum);
}

// ---------------- x_update = (q @ kv) * m[n] * scale; m computed inline from q,kso,si ----------------
__global__ __launch_bounds__(256) void k_xup(
    const u16* __restrict__ qkv, const float* __restrict__ kvm,
    const float* __restrict__ si_arr, const float* __restrict__ kso,
    const float* __restrict__ sumexp,
    u16* __restrict__ attn)
{
  const int bh = blockIdx.y;
  const int n0 = blockIdx.x << 7;
  const int b = bh / 12, h = bh % 12;
  __shared__ __align__(16) u16 qs[128 * 72];
  __shared__ __align__(16) u16 kvs[64 * 72];
  __shared__ float m_lds[128];
  const int tid = threadIdx.x, lane = tid & 63, wid = tid >> 6;
  const int d0c = (tid & 7) << 3;

  // soe + block-uniform cS (same math as reference flow2 path)
  float soe[8];
#pragma unroll
  for (int u = 0; u < 8; ++u) soe[u] = kso[(bh << 6) + d0c + u] + EPSF;
  float Ss = 0.f;
#pragma unroll
  for (int u = 0; u < 8; ++u) Ss += soe[u];
#pragma unroll
  for (int m = 1; m < 8; m <<= 1) Ss += __shfl_xor(Ss, m, 64);
  const float cS = EPSF * Ss + EPSF;

  const u16* qg = qkv + (size_t)b * 4096 * 2304 + (size_t)n0 * 2304 + h * 64;
#pragma unroll
  for (int i = 0; i < 4; ++i) {
    const int c = tid + (i << 8);
    const int nl = c >> 3, d0 = (c & 7) << 3;
    short8 q8 = *(const short8*)(qg + (size_t)nl * 2304 + d0);
    *(short8*)&qs[nl * 72 + d0] = q8;
    float pcs = 0.f;
#pragma unroll
    for (int u = 0; u < 8; ++u) pcs += us2f((u16)q8[u]) * soe[u];
#pragma unroll
    for (int m = 1; m < 8; m <<= 1) pcs += __shfl_xor(pcs, m, 64);
    if ((tid & 7) == 0)
      m_lds[nl] = si_arr[((size_t)bh << 12) + n0 + nl] * sigm(pcs + cS);
  }
  const float* kvg = kvm + ((size_t)bh << 12);
#pragma unroll
  for (int i = 0; i < 4; ++i) {
    const int idx = (tid << 2) + (i << 10);
    const int d = idx >> 6, e0 = idx & 63;
    float4 vv = *(const float4*)(kvg + idx);
    kvs[(e0 + 0) * 72 + d] = f2bfu(vv.x);
    kvs[(e0 + 1) * 72 + d] = f2bfu(vv.y);
    kvs[(e0 + 2) * 72 + d] = f2bfu(vv.z);
    kvs[(e0 + 3) * 72 + d] = f2bfu(vv.w);
  }
  __syncthreads();
  const float scale = 4096.f / sumexp[bh];
  const int r16 = lane & 15, kg8 = (lane >> 4) << 3;
  f32x4 acc[2][4];
#pragma unroll
  for (int i = 0; i < 2; ++i)
#pragma unroll
    for (int j = 0; j < 4; ++j) acc[i][j] = (f32x4){0.f, 0.f, 0.f, 0.f};
#pragma unroll
  for (int kk = 0; kk < 2; ++kk) {
    short8 af[2], bfv[4];
#pragma unroll
    for (int mi = 0; mi < 2; ++mi)
      af[mi] = *(const short8*)&qs[((wid << 5) + (mi << 4) + r16) * 72 + (kk << 5) + kg8];
#pragma unroll
    for (int nj = 0; nj < 4; ++nj)
      bfv[nj] = *(const short8*)&kvs[((nj << 4) + r16) * 72 + (kk << 5) + kg8];
#pragma unroll
    for (int mi = 0; mi < 2; ++mi)
#pragma unroll
      for (int nj = 0; nj < 4; ++nj)
        acc[mi][nj] = __builtin_amdgcn_mfma_f32_16x16x32_bf16(af[mi], bfv[nj], acc[mi][nj], 0, 0, 0);
  }
#pragma unroll
  for (int mi = 0; mi < 2; ++mi) {
#pragma unroll
    for (int rg = 0; rg < 4; ++rg) {
      const int nloc = (wid << 5) + (mi << 4) + ((lane >> 4) << 2) + rg;
      const int n = n0 + nloc;
      const float mult = m_lds[nloc] * scale;
#pragma unroll
      for (int nj = 0; nj < 4; ++nj) {
        const int e = (nj << 4) + r16;
        attn[((size_t)(b * 4096 + n)) * 768 + (h << 6) + e] = f2bfu(acc[mi][nj][rg] * mult);
      }
    }
  }
}

extern "C" void kernel_launch(void* const* d_in, const int* in_sizes, int n_in,
                              void* d_out, int out_size, void* d_ws, size_t ws_size,
                              hipStream_t stream)
{
  (void)in_sizes; (void)n_in; (void)out_size; (void)ws_size;
  const float* x     = (const float*)d_in[0];
  const float* Wqkv  = (const float*)d_in[1];
  const float* bqkv  = (const float*)d_in[2];
  const float* Wproj = (const float*)d_in[3];
  const float* bproj = (const float*)d_in[4];
  float* out = (float*)d_out;

  char* ws = (char*)d_ws;
  size_t off = 0;
  auto alloc = [&](size_t bytes) -> char* {
    char* p = ws + off;
    off += (bytes + 255) & ~(size_t)255;
    return p;
  };
  u16* qkv  = (u16*)alloc(150994944);      // [32768][2304] bf16 flat (q|k|v)
  u16* xbf  = (u16*)alloc(50331648);       // x bf16; reused as attn output
  u16* WqT  = (u16*)alloc(3538944);        // [2304][768] bf16
  u16* WpT  = (u16*)alloc(1179648);        // [768][768] bf16
  float* si = (float*)alloc(1572864);      // [B*H][N]
  char* zbase = ws + off;
  float* qsum   = (float*)alloc(24576);
  float* ksum   = (float*)alloc(24576);
  float* qsi    = (float*)alloc(24576);
  float* kso    = (float*)alloc(24576);
  float* sumexp = (float*)alloc(512);
  float* kvm    = (float*)alloc(1572864);  // [B*H][64 d][64 e] f32
  const size_t zbytes = (size_t)((ws + off) - zbase);

  hipMemsetAsync(zbase, 0, zbytes, stream);
  k_prep<<<26880, 256, 0, stream>>>(x, xbf, Wqkv, WqT, Wproj, WpT);
  k_gemm<0><<<dim3(9, 128), 512, 0, stream>>>(xbf, WqT, bqkv, qkv, qsum, ksum, nullptr);
  k_flow1<<<768, 256, 0, stream>>>(qkv, qsum, ksum, si, qsi, kso);
  k_fkv<<<768, 256, 0, stream>>>(qkv, qsi, sumexp, kvm);
  k_xup<<<dim3(32, 96), 256, 0, stream>>>(qkv, kvm, si, kso, sumexp, xbf);
  k_gemm<1><<<dim3(3, 128), 512, 0, stream>>>(xbf, WpT, bproj, nullptr, nullptr, nullptr, out);
}

// Round 12
// 375.960 us; speedup vs baseline: 1.1226x; 1.0422x over previous
//
#include <hip/hip_runtime.h>
#include <stdint.h>

#define EPSF 1e-6f

typedef unsigned short u16;
typedef __attribute__((ext_vector_type(8))) short short8;
typedef __attribute__((ext_vector_type(4))) float f32x4;

__device__ __forceinline__ float us2f(u16 u) {
  union { float f; unsigned int i; } c; c.i = ((unsigned int)u) << 16; return c.f;
}
__device__ __forceinline__ u16 f2bfu(float f) {
  union { float f; unsigned int i; } c; c.f = f;
  unsigned int i = c.i;
  return (u16)((i + 0x7FFFu + ((i >> 16) & 1u)) >> 16);
}
__device__ __forceinline__ float sigm(float x) { return 1.f / (1.f + __expf(-x)); }

typedef __attribute__((address_space(3))) unsigned int lds_u32;
typedef const __attribute__((address_space(1))) unsigned int glb_u32;
__device__ __forceinline__ void gl_lds16(const u16* g, u16* l) {
  __builtin_amdgcn_global_load_lds((glb_u32*)g, (lds_u32*)l, 16, 0, 0);
}

// ---------------- fused prep: x cvt (blocks 0..24575) + W transposes ----------------
__global__ void k_prep(const float* __restrict__ x, u16* __restrict__ xbf,
                       const float* __restrict__ Wqkv, u16* __restrict__ WqT,
                       const float* __restrict__ Wproj, u16* __restrict__ WpT) {
  __shared__ float tile[32][33];
  const int b = blockIdx.x;
  if (b < 24576) {
    const int i = b * 256 + threadIdx.x;
    float4 v = ((const float4*)x)[i];
    ushort4 o;
    o.x = f2bfu(v.x); o.y = f2bfu(v.y); o.z = f2bfu(v.z); o.w = f2bfu(v.w);
    ((ushort4*)xbf)[i] = o;
    return;
  }
  const float* in; u16* out; int R, C, bx, by;
  if (b < 24576 + 1728) {
    const int id = b - 24576; in = Wqkv; out = WqT; R = 768; C = 2304; bx = id % 72; by = id / 72;
  } else {
    const int id = b - 26304; in = Wproj; out = WpT; R = 768; C = 768; bx = id % 24; by = id / 24;
  }
  const int tx = threadIdx.x & 31, ty = threadIdx.x >> 5;
  const int c0 = bx << 5, r0 = by << 5;
  for (int i = ty; i < 32; i += 8) tile[i][tx] = in[(size_t)(r0 + i) * C + c0 + tx];
  __syncthreads();
  for (int i = ty; i < 32; i += 8) out[(size_t)(c0 + i) * R + r0 + tx] = f2bfu(tile[tx][i]);
}

// ---------------- GEMM: 256x192 tile, 8 waves, BK=64, 4-phase/tile ----------------
// Same frozen schedule as round-10/11; tile re-shaped so grids divide 256 CUs exactly:
// gemm<0> (12,128)=1536=6.0 rounds, gemm<1> (4,128)=512=2.0 rounds (was 4.5 / 1.5).
// LDS per dbuf: A 2x8192-elem units (128 rows) + B 3x4096-elem units (64 rows) = 56KB; x2 = 112KB.
// XOR chunk swizzle key row&7 (48,16 === 0 mod 8 -> key == r16&7 on reads). Bit-identical K-order.
template <int MODE>
__global__ __launch_bounds__(512, 1) void k_gemm(
    const u16* __restrict__ A, const u16* __restrict__ BT,
    const float* __restrict__ bias,
    u16* __restrict__ qkvo, float* __restrict__ qsum, float* __restrict__ ksum,
    float* __restrict__ outf)
{
  __shared__ __align__(16) u16 smem[57344];  // 112 KB
  const int tid = threadIdx.x;
  const int lane = tid & 63;
  const int wid = tid >> 6;           // 0..7
  const int wm = wid >> 2, wn = wid & 3;
  // bijective XCD swizzle (nwg % 8 == 0 for both grids)
  const int nx = gridDim.x;
  int lid = blockIdx.y * nx + blockIdx.x;
  const int q8 = (nx * gridDim.y) >> 3;
  lid = (lid & 7) * q8 + (lid >> 3);
  const int m0 = (lid / nx) << 8;
  const int n0 = (lid % nx) * 192;

  const int rowL0 = tid >> 3;                      // 0..63
  const int gc = (tid & 7) ^ (rowL0 & 7);
  const u16* gA = A  + (size_t)(m0 + rowL0) * 768 + (gc << 3);
  const u16* gB = BT + (size_t)(n0 + rowL0) * 768 + (gc << 3);

  const int r16 = lane & 15;
  const int sgrp = lane >> 4;
  const int xk = r16 & 7;
  const int coff0 = ((sgrp) ^ xk) << 3;            // kslot 0 chunk offset (elems)
  const int coff1 = ((4 + sgrp) ^ xk) << 3;        // kslot 1
  int offB[3];
#pragma unroll
  for (int nj = 0; nj < 3; ++nj) {
    const int ub = wn * 48 + (nj << 4);            // 16-row band base (never straddles 64)
    offB[nj] = ((ub >> 6) << 12) + (((ub & 63) + r16) << 6);
  }

  f32x4 acc[8][3];
#pragma unroll
  for (int i = 0; i < 8; ++i)
#pragma unroll
    for (int j = 0; j < 3; ++j) acc[i][j] = (f32x4){0.f, 0.f, 0.f, 0.f};

#define STAGEA(tt, y)                                                         \
  do {                                                                        \
    u16* dst = &smem[(((tt) & 1) * 28672) + ((y) << 13) + (tid << 3)];        \
    const u16* s = gA + (size_t)(y) * 98304 + (tt) * 64;                      \
    gl_lds16(s, dst);                                                         \
    gl_lds16(s + 49152, dst + 4096);                                          \
  } while (0)

#define STAGEB(tt, u)                                                         \
  do {                                                                        \
    u16* dst = &smem[(((tt) & 1) * 28672) + 16384 + ((u) << 12) + (tid << 3)];\
    gl_lds16(gB + (size_t)(u) * 49152 + (tt) * 64, dst);                      \
  } while (0)

#define RDA(mi, co) (*(const short8*)(pa + ((((mi) << 4) + r16) << 6) + (co)))
#define RDB(nj, co) (*(const short8*)(pb + offB[nj] + (co)))

#define MFMA12(P, A00, A01, A10, A11)                                                               \
  do {                                                                                              \
    acc[2*(P)  ][0] = __builtin_amdgcn_mfma_f32_16x16x32_bf16(A00, bf[0][0], acc[2*(P)  ][0],0,0,0);\
    acc[2*(P)  ][1] = __builtin_amdgcn_mfma_f32_16x16x32_bf16(A00, bf[1][0], acc[2*(P)  ][1],0,0,0);\
    acc[2*(P)  ][2] = __builtin_amdgcn_mfma_f32_16x16x32_bf16(A00, bf[2][0], acc[2*(P)  ][2],0,0,0);\
    acc[2*(P)+1][0] = __builtin_amdgcn_mfma_f32_16x16x32_bf16(A10, bf[0][0], acc[2*(P)+1][0],0,0,0);\
    acc[2*(P)+1][1] = __builtin_amdgcn_mfma_f32_16x16x32_bf16(A10, bf[1][0], acc[2*(P)+1][1],0,0,0);\
    acc[2*(P)+1][2] = __builtin_amdgcn_mfma_f32_16x16x32_bf16(A10, bf[2][0], acc[2*(P)+1][2],0,0,0);\
    acc[2*(P)  ][0] = __builtin_amdgcn_mfma_f32_16x16x32_bf16(A01, bf[0][1], acc[2*(P)  ][0],0,0,0);\
    acc[2*(P)  ][1] = __builtin_amdgcn_mfma_f32_16x16x32_bf16(A01, bf[1][1], acc[2*(P)  ][1],0,0,0);\
    acc[2*(P)  ][2] = __builtin_amdgcn_mfma_f32_16x16x32_bf16(A01, bf[2][1], acc[2*(P)  ][2],0,0,0);\
    acc[2*(P)+1][0] = __builtin_amdgcn_mfma_f32_16x16x32_bf16(A11, bf[0][1], acc[2*(P)+1][0],0,0,0);\
    acc[2*(P)+1][1] = __builtin_amdgcn_mfma_f32_16x16x32_bf16(A11, bf[1][1], acc[2*(P)+1][1],0,0,0);\
    acc[2*(P)+1][2] = __builtin_amdgcn_mfma_f32_16x16x32_bf16(A11, bf[2][1], acc[2*(P)+1][2],0,0,0);\
  } while (0)

#define PH_SYNC_PRE()                                          \
    __builtin_amdgcn_s_barrier();                              \
    asm volatile("s_waitcnt lgkmcnt(0)" ::: "memory");         \
    __builtin_amdgcn_sched_barrier(0);                         \
    __builtin_amdgcn_s_setprio(1)

#define PH_SYNC_POST()                                         \
    __builtin_amdgcn_s_setprio(0);                             \
    __builtin_amdgcn_sched_barrier(0);                         \
    __builtin_amdgcn_s_barrier()

  STAGEA(0, 0); STAGEA(0, 1); STAGEB(0, 0); STAGEB(0, 1); STAGEB(0, 2);
  asm volatile("s_waitcnt vmcnt(0)" ::: "memory");
  __builtin_amdgcn_s_barrier();

  for (int t = 0; t < 12; ++t) {
    const u16* pa = &smem[(t & 1) * 28672 + (wm << 13)];
    const u16* pb = &smem[(t & 1) * 28672 + 16384];
    short8 bf[3][2];
    bf[0][0] = RDB(0, coff0); bf[0][1] = RDB(0, coff1);
    bf[1][0] = RDB(1, coff0); bf[1][1] = RDB(1, coff1);
    bf[2][0] = RDB(2, coff0); bf[2][1] = RDB(2, coff1);
    short8 a00 = RDA(0, coff0), a01 = RDA(0, coff1);
    short8 a10 = RDA(1, coff0), a11 = RDA(1, coff1);
    if (t < 11) { STAGEA(t + 1, 0); STAGEA(t + 1, 1); }
    PH_SYNC_PRE();
    MFMA12(0, a00, a01, a10, a11);
    PH_SYNC_POST();
    a00 = RDA(2, coff0); a01 = RDA(2, coff1);
    a10 = RDA(3, coff0); a11 = RDA(3, coff1);
    if (t < 11) { STAGEB(t + 1, 0); STAGEB(t + 1, 1); STAGEB(t + 1, 2); }
    PH_SYNC_PRE();
    MFMA12(1, a00, a01, a10, a11);
    PH_SYNC_POST();
    a00 = RDA(4, coff0); a01 = RDA(4, coff1);
    a10 = RDA(5, coff0); a11 = RDA(5, coff1);
    PH_SYNC_PRE();
    MFMA12(2, a00, a01, a10, a11);
    PH_SYNC_POST();
    a00 = RDA(6, coff0); a01 = RDA(6, coff1);
    a10 = RDA(7, coff0); a11 = RDA(7, coff1);
    PH_SYNC_PRE();
    MFMA12(3, a00, a01, a10, a11);
    __builtin_amdgcn_s_setprio(0);
    __builtin_amdgcn_sched_barrier(0);
    asm volatile("s_waitcnt vmcnt(0)" ::: "memory");  // next tile landed (issued >=2 phases ago)
    __builtin_amdgcn_s_barrier();
  }
#undef PH_SYNC_PRE
#undef PH_SYNC_POST
#undef MFMA12
#undef RDA
#undef RDB
#undef STAGEA
#undef STAGEB

  if (MODE == 0) {
    // tile is entirely q (n0<768), k (768<=n0<1536) or v (n0>=1536): 768 = 4*192
    const bool sg = (n0 < 1536);
    const int colc = n0 + wn * 48;
    float jsum[3] = {0.f, 0.f, 0.f};
#pragma unroll
    for (int mi = 0; mi < 8; ++mi) {
      const int rowb = m0 + (wm << 7) + (mi << 4) + ((lane >> 4) << 2);
#pragma unroll
      for (int nj = 0; nj < 3; ++nj) {
        const int col = colc + (nj << 4) + r16;
        const float bcol = bias[col];
        if (sg) {
#pragma unroll
          for (int rg = 0; rg < 4; ++rg) {
            const float val = sigm(acc[mi][nj][rg] + bcol);
            jsum[nj] += val;
            qkvo[(size_t)(rowb + rg) * 2304 + col] = f2bfu(val);
          }
        } else {
#pragma unroll
          for (int rg = 0; rg < 4; ++rg)
            qkvo[(size_t)(rowb + rg) * 2304 + col] = f2bfu(acc[mi][nj][rg] + bcol);
        }
      }
    }
    if (sg) {
#pragma unroll
      for (int nj = 0; nj < 3; ++nj) {
        jsum[nj] += __shfl_xor(jsum[nj], 16, 64);
        jsum[nj] += __shfl_xor(jsum[nj], 32, 64);
      }
      if (lane < 16) {
        const int b768 = (m0 >> 12) * 768;
        float* sdst = (n0 >= 768) ? ksum : qsum;
        const int cb = colc - ((n0 >= 768) ? 768 : 0);
#pragma unroll
        for (int nj = 0; nj < 3; ++nj)
          atomicAdd(&sdst[b768 + cb + (nj << 4) + r16], jsum[nj]);
      }
    }
  } else {
#pragma unroll
    for (int mi = 0; mi < 8; ++mi) {
      const int rowb = m0 + (wm << 7) + (mi << 4) + ((lane >> 4) << 2);
#pragma unroll
      for (int nj = 0; nj < 3; ++nj) {
        const int col = n0 + wn * 48 + (nj << 4) + r16;
        const float bcol = bias[col];
#pragma unroll
        for (int rg = 0; rg < 4; ++rg)
          outf[(size_t)(rowb + rg) * 768 + col] = sigm(2.f * (acc[mi][nj][rg] + bcol));
      }
    }
  }
}

// ---------------- si/so + qsi/kso: 8-lane groups, 16B loads ----------------
__global__ __launch_bounds__(256) void k_flow1(
    const u16* __restrict__ qkv,
    const float* __restrict__ qsum, const float* __restrict__ ksum,
    float* __restrict__ si_out, float* __restrict__ qsi, float* __restrict__ kso)
{
  const int bh = blockIdx.x >> 3, sp = blockIdx.x & 7;
  const int tid = threadIdx.x;
  const int grp = tid >> 3;
  const int d0 = (tid & 7) << 3;
  const u16* base = qkv + (size_t)(bh / 12) * 4096 * 2304 + (bh % 12) * 64;

  float ke[8], qe[8];
#pragma unroll
  for (int u = 0; u < 8; ++u) {
    ke[u] = ksum[(bh << 6) + d0 + u] + EPSF;
    qe[u] = qsum[(bh << 6) + d0 + u] + EPSF;
  }
  float Sk = 0.f, Sq = 0.f;
#pragma unroll
  for (int u = 0; u < 8; ++u) { Sk += ke[u]; Sq += qe[u]; }
#pragma unroll
  for (int m = 1; m < 8; m <<= 1) { Sk += __shfl_xor(Sk, m, 64); Sq += __shfl_xor(Sq, m, 64); }
  const float cK = EPSF * Sk + EPSF;
  const float cQ = EPSF * Sq + EPSF;

  float aq[8], ak[8];
#pragma unroll
  for (int u = 0; u < 8; ++u) { aq[u] = 0.f; ak[u] = 0.f; }

  const int nbase = sp << 9;
  for (int it = 0; it < 16; ++it) {
    const int n = nbase + (it << 5) + grp;
    const u16* rp = base + (size_t)n * 2304 + d0;
    short8 q8 = *(const short8*)(rp);
    short8 k8 = *(const short8*)(rp + 768);
    float dq = 0.f, dk = 0.f;
#pragma unroll
    for (int u = 0; u < 8; ++u) {
      dq += us2f((u16)q8[u]) * ke[u];
      dk += us2f((u16)k8[u]) * qe[u];
    }
#pragma unroll
    for (int m = 1; m < 8; m <<= 1) { dq += __shfl_xor(dq, m, 64); dk += __shfl_xor(dk, m, 64); }
    const float si = 1.f / (dq + cK);
    const float so = 1.f / (dk + cQ);
    if ((tid & 7) == 0) si_out[(bh << 12) + n] = si;
#pragma unroll
    for (int u = 0; u < 8; ++u) {
      aq[u] += us2f((u16)q8[u]) * si;
      ak[u] += us2f((u16)k8[u]) * so;
    }
  }
  __shared__ float redq[32][68];
  __shared__ float redk[32][68];
#pragma unroll
  for (int u = 0; u < 8; ++u) { redq[grp][d0 + u] = aq[u]; redk[grp][d0 + u] = ak[u]; }
  __syncthreads();
  if (tid < 128) {
    const int which = tid >> 6, d = tid & 63;
    float s = 0.f;
    if (which == 0) {
#pragma unroll
      for (int g = 0; g < 32; ++g) s += redq[g][d];
      atomicAdd(&qsi[(bh << 6) + d], s);
    } else {
#pragma unroll
      for (int g = 0; g < 32; ++g) s += redk[g][d];
      atomicAdd(&kso[(bh << 6) + d], s);
    }
  }
}

// ---------------- fused kv (MFMA): e/sumexp inline, kvm[d][e] accumulate ----------------
__global__ __launch_bounds__(256) void k_fkv(
    const u16* __restrict__ qkv,
    const float* __restrict__ qsi,
    float* __restrict__ sumexp, float* __restrict__ kvm)
{
  __shared__ __align__(16) u16 smem[2 * 64 * 136];  // 34816 B; reused as f32 reduce buf
  u16* kT = smem;
  u16* vT = smem + 64 * 136;
  const int tid = threadIdx.x;
  const int bh = blockIdx.x >> 3, sp = blockIdx.x & 7;
  const int lane = tid & 63, wid = tid >> 6;
  const int r16 = lane & 15, g = lane >> 4;
  const u16* base = qkv + (size_t)(bh / 12) * 4096 * 2304 + (bh % 12) * 64;

  const int d0 = (tid & 7) << 3;
  float qie[8];
#pragma unroll
  for (int u = 0; u < 8; ++u) qie[u] = qsi[(bh << 6) + d0 + u] + EPSF;
  float Sq = qsi[(bh << 6) + lane] + EPSF;
#pragma unroll
  for (int m = 1; m < 64; m <<= 1) Sq += __shfl_xor(Sq, m, 64);
  const float cR = EPSF * Sq + EPSF;

  f32x4 acc[4][4];
#pragma unroll
  for (int i = 0; i < 4; ++i)
#pragma unroll
    for (int j = 0; j < 4; ++j) acc[i][j] = (f32x4){0.f, 0.f, 0.f, 0.f};

  const int nf = (wid << 5) + (g << 3);
  float esum = 0.f;

  for (int st = 0; st < 4; ++st) {
    const int nst = (sp << 9) + (st << 7);
#pragma unroll
    for (int i = 0; i < 4; ++i) {
      const int c = tid + (i << 8);
      const int nl = c >> 3;
      const int ng = nst + nl;
      const u16* rp = base + (size_t)ng * 2304 + d0;
      short8 k8 = *(const short8*)(rp + 768);
      short8 v8 = *(const short8*)(rp + 1536);
      float pcr = 0.f;
#pragma unroll
      for (int u = 0; u < 8; ++u) pcr += us2f((u16)k8[u]) * qie[u];
#pragma unroll
      for (int m = 1; m < 8; m <<= 1) pcr += __shfl_xor(pcr, m, 64);
      float cr = pcr + cR;
      cr = fminf(1.f, fmaxf(-1.f, cr));
      const float ev = __expf(cr);
      const int col = nl ^ (d0 & 56);
#pragma unroll
      for (int u = 0; u < 8; ++u) {
        kT[(d0 + u) * 136 + col] = f2bfu(us2f((u16)k8[u]) * ev);
        vT[(d0 + u) * 136 + col] = (u16)(unsigned short)v8[u];
      }
      if ((tid & 7) == 0) esum += ev;
    }
    __syncthreads();

    short8 af[4], bf[4];
#pragma unroll
    for (int mi = 0; mi < 4; ++mi) {
      const int row = (mi << 4) + r16;
      af[mi] = *(const short8*)&kT[row * 136 + (nf ^ (row & 56))];
    }
#pragma unroll
    for (int nj = 0; nj < 4; ++nj) {
      const int row = (nj << 4) + r16;
      bf[nj] = *(const short8*)&vT[row * 136 + (nf ^ (row & 56))];
    }
#pragma unroll
    for (int mi = 0; mi < 4; ++mi)
#pragma unroll
      for (int nj = 0; nj < 4; ++nj)
        acc[mi][nj] = __builtin_amdgcn_mfma_f32_16x16x32_bf16(af[mi], bf[nj], acc[mi][nj], 0, 0, 0);
    __syncthreads();
  }

  // cross-wave reduce (two 32-d halves through LDS) + coalesced atomics
  float* red = (float*)smem;
  float* kvb = kvm + ((size_t)bh << 12);
#pragma unroll
  for (int half = 0; half < 2; ++half) {
#pragma unroll
    for (int m2 = 0; m2 < 2; ++m2) {
      const int mi = (half << 1) + m2;
#pragma unroll
      for (int nj = 0; nj < 4; ++nj)
#pragma unroll
        for (int rg = 0; rg < 4; ++rg)
          red[(wid << 11) + (((m2 << 4) + (g << 2) + rg) << 6) + (nj << 4) + r16] = acc[mi][nj][rg];
    }
    __syncthreads();
    const int base2 = tid << 3;
#pragma unroll
    for (int u2 = 0; u2 < 2; ++u2) {
      const int o = base2 + (u2 << 2);
      float4 s0 = *(const float4*)&red[o];
      float4 s1 = *(const float4*)&red[2048 + o];
      float4 s2 = *(const float4*)&red[4096 + o];
      float4 s3 = *(const float4*)&red[6144 + o];
      s0.x += s1.x + s2.x + s3.x;
      s0.y += s1.y + s2.y + s3.y;
      s0.z += s1.z + s2.z + s3.z;
      s0.w += s1.w + s2.w + s3.w;
      const int gi = (half << 11) + o;
      atomicAdd(&kvb[gi + 0], s0.x);
      atomicAdd(&kvb[gi + 1], s0.y);
      atomicAdd(&kvb[gi + 2], s0.z);
      atomicAdd(&kvb[gi + 3], s0.w);
    }
    __syncthreads();
  }

  esum += __shfl_xor(esum, 8, 64);
  esum += __shfl_xor(esum, 16, 64);
  esum += __shfl_xor(esum, 32, 64);
  if (lane == 0) atomicAdd(&sumexp[bh], esum);
}

// ---------------- x_update = (q @ kv) * m[n] * scale; m computed inline from q,kso,si ----------------
__global__ __launch_bounds__(256) void k_xup(
    const u16* __restrict__ qkv, const float* __restrict__ kvm,
    const float* __restrict__ si_arr, const float* __restrict__ kso,
    const float* __restrict__ sumexp,
    u16* __restrict__ attn)
{
  const int bh = blockIdx.y;
  const int n0 = blockIdx.x << 7;
  const int b = bh / 12, h = bh % 12;
  __shared__ __align__(16) u16 qs[128 * 72];
  __shared__ __align__(16) u16 kvs[64 * 72];
  __shared__ float m_lds[128];
  const int tid = threadIdx.x, lane = tid & 63, wid = tid >> 6;
  const int d0c = (tid & 7) << 3;

  float soe[8];
#pragma unroll
  for (int u = 0; u < 8; ++u) soe[u] = kso[(bh << 6) + d0c + u] + EPSF;
  float Ss = 0.f;
#pragma unroll
  for (int u = 0; u < 8; ++u) Ss += soe[u];
#pragma unroll
  for (int m = 1; m < 8; m <<= 1) Ss += __shfl_xor(Ss, m, 64);
  const float cS = EPSF * Ss + EPSF;

  const u16* qg = qkv + (size_t)b * 4096 * 2304 + (size_t)n0 * 2304 + h * 64;
#pragma unroll
  for (int i = 0; i < 4; ++i) {
    const int c = tid + (i << 8);
    const int nl = c >> 3, d0 = (c & 7) << 3;
    short8 q8 = *(const short8*)(qg + (size_t)nl * 2304 + d0);
    *(short8*)&qs[nl * 72 + d0] = q8;
    float pcs = 0.f;
#pragma unroll
    for (int u = 0; u < 8; ++u) pcs += us2f((u16)q8[u]) * soe[u];
#pragma unroll
    for (int m = 1; m < 8; m <<= 1) pcs += __shfl_xor(pcs, m, 64);
    if ((tid & 7) == 0)
      m_lds[nl] = si_arr[((size_t)bh << 12) + n0 + nl] * sigm(pcs + cS);
  }
  const float* kvg = kvm + ((size_t)bh << 12);
#pragma unroll
  for (int i = 0; i < 4; ++i) {
    const int idx = (tid << 2) + (i << 10);
    const int d = idx >> 6, e0 = idx & 63;
    float4 vv = *(const float4*)(kvg + idx);
    kvs[(e0 + 0) * 72 + d] = f2bfu(vv.x);
    kvs[(e0 + 1) * 72 + d] = f2bfu(vv.y);
    kvs[(e0 + 2) * 72 + d] = f2bfu(vv.z);
    kvs[(e0 + 3) * 72 + d] = f2bfu(vv.w);
  }
  __syncthreads();
  const float scale = 4096.f / sumexp[bh];
  const int r16 = lane & 15, kg8 = (lane >> 4) << 3;
  f32x4 acc[2][4];
#pragma unroll
  for (int i = 0; i < 2; ++i)
#pragma unroll
    for (int j = 0; j < 4; ++j) acc[i][j] = (f32x4){0.f, 0.f, 0.f, 0.f};
#pragma unroll
  for (int kk = 0; kk < 2; ++kk) {
    short8 af[2], bfv[4];
#pragma unroll
    for (int mi = 0; mi < 2; ++mi)
      af[mi] = *(const short8*)&qs[((wid << 5) + (mi << 4) + r16) * 72 + (kk << 5) + kg8];
#pragma unroll
    for (int nj = 0; nj < 4; ++nj)
      bfv[nj] = *(const short8*)&kvs[((nj << 4) + r16) * 72 + (kk << 5) + kg8];
#pragma unroll
    for (int mi = 0; mi < 2; ++mi)
#pragma unroll
      for (int nj = 0; nj < 4; ++nj)
        acc[mi][nj] = __builtin_amdgcn_mfma_f32_16x16x32_bf16(af[mi], bfv[nj], acc[mi][nj], 0, 0, 0);
  }
#pragma unroll
  for (int mi = 0; mi < 2; ++mi) {
#pragma unroll
    for (int rg = 0; rg < 4; ++rg) {
      const int nloc = (wid << 5) + (mi << 4) + ((lane >> 4) << 2) + rg;
      const int n = n0 + nloc;
      const float mult = m_lds[nloc] * scale;
#pragma unroll
      for (int nj = 0; nj < 4; ++nj) {
        const int e = (nj << 4) + r16;
        attn[((size_t)(b * 4096 + n)) * 768 + (h << 6) + e] = f2bfu(acc[mi][nj][rg] * mult);
      }
    }
  }
}

extern "C" void kernel_launch(void* const* d_in, const int* in_sizes, int n_in,
                              void* d_out, int out_size, void* d_ws, size_t ws_size,
                              hipStream_t stream)
{
  (void)in_sizes; (void)n_in; (void)out_size; (void)ws_size;
  const float* x     = (const float*)d_in[0];
  const float* Wqkv  = (const float*)d_in[1];
  const float* bqkv  = (const float*)d_in[2];
  const float* Wproj = (const float*)d_in[3];
  const float* bproj = (const float*)d_in[4];
  float* out = (float*)d_out;

  char* ws = (char*)d_ws;
  size_t off = 0;
  auto alloc = [&](size_t bytes) -> char* {
    char* p = ws + off;
    off += (bytes + 255) & ~(size_t)255;
    return p;
  };
  u16* qkv  = (u16*)alloc(150994944);      // [32768][2304] bf16 flat (q|k|v)
  u16* xbf  = (u16*)alloc(50331648);       // x bf16; reused as attn output
  u16* WqT  = (u16*)alloc(3538944);        // [2304][768] bf16
  u16* WpT  = (u16*)alloc(1179648);        // [768][768] bf16
  float* si = (float*)alloc(1572864);      // [B*H][N]
  char* zbase = ws + off;
  float* qsum   = (float*)alloc(24576);
  float* ksum   = (float*)alloc(24576);
  float* qsi    = (float*)alloc(24576);
  float* kso    = (float*)alloc(24576);
  float* sumexp = (float*)alloc(512);
  float* kvm    = (float*)alloc(1572864);  // [B*H][64 d][64 e] f32
  const size_t zbytes = (size_t)((ws + off) - zbase);

  hipMemsetAsync(zbase, 0, zbytes, stream);
  k_prep<<<26880, 256, 0, stream>>>(x, xbf, Wqkv, WqT, Wproj, WpT);
  k_gemm<0><<<dim3(12, 128), 512, 0, stream>>>(xbf, WqT, bqkv, qkv, qsum, ksum, nullptr);
  k_flow1<<<768, 256, 0, stream>>>(qkv, qsum, ksum, si, qsi, kso);
  k_fkv<<<768, 256, 0, stream>>>(qkv, qsi, sumexp, kvm);
  k_xup<<<dim3(32, 96), 256, 0, stream>>>(qkv, kvm, si, kso, sumexp, xbf);
  k_gemm<1><<<dim3(4, 128), 512, 0, stream>>>(xbf, WpT, bproj, nullptr, nullptr, nullptr, out);
}